// Round 1
// baseline (3180.073 us; speedup 1.0000x reference)
//
#include <hip/hip_runtime.h>
#include <hip/hip_bf16.h>
#include <math.h>

#define NFEAT 512
#define H1 300
#define H2 200
#define NCLASS 40

// ---------------- CSR construction ----------------

__global__ __launch_bounds__(256) void count_dst_kernel(const int* __restrict__ dst,
                                                        int* __restrict__ counts, int E) {
    int i = blockIdx.x * blockDim.x + threadIdx.x;
    if (i < E) atomicAdd(&counts[dst[i]], 1);
}

// single-block inclusive scan -> exclusive row_ptr
__global__ __launch_bounds__(1024) void scan_kernel(const int* __restrict__ counts,
                                                    int* __restrict__ row_ptr, int N) {
    __shared__ int sdata[1024];
    __shared__ int carry_s;
    int tid = threadIdx.x;
    if (tid == 0) { carry_s = 0; row_ptr[0] = 0; }
    __syncthreads();
    for (int base = 0; base < N; base += 1024) {
        int i = base + tid;
        int v = (i < N) ? counts[i] : 0;
        sdata[tid] = v;
        __syncthreads();
        #pragma unroll
        for (int off = 1; off < 1024; off <<= 1) {
            int t = (tid >= off) ? sdata[tid - off] : 0;
            __syncthreads();
            sdata[tid] += t;
            __syncthreads();
        }
        int carry = carry_s;
        if (i < N) row_ptr[i + 1] = sdata[tid] + carry;
        __syncthreads();
        if (tid == 1023) carry_s = carry + sdata[1023];
        __syncthreads();
    }
}

__global__ __launch_bounds__(256) void fill_csr_kernel(const int* __restrict__ src,
                                                       const int* __restrict__ dst,
                                                       const float* __restrict__ ew,
                                                       int* __restrict__ next,
                                                       int* __restrict__ csr_src,
                                                       float* __restrict__ csr_w, int E) {
    int i = blockIdx.x * blockDim.x + threadIdx.x;
    if (i < E) {
        int d = dst[i];
        int pos = atomicAdd(&next[d], 1);
        csr_src[pos] = src[i];
        csr_w[pos]   = ew[i];
    }
}

// ---------------- fp32 tiled GEMM: C[MxN] = A[MxK] @ B[KxN] ----------------
// block 256 threads = 16x16 thread grid, each thread 4x4; tile 64x64, K-tile 16.

__global__ __launch_bounds__(256) void gemm_f32_kernel(const float* __restrict__ A,
                                                       const float* __restrict__ B,
                                                       float* __restrict__ C,
                                                       int M, int N, int K) {
    __shared__ float As[16][68];  // [kk][mm], pad 68 keeps 16B alignment for b128 reads
    __shared__ float Bs[16][64];  // [kk][nn]
    const int bm = blockIdx.y * 64;
    const int bn = blockIdx.x * 64;
    const int tid = threadIdx.x;
    const int tr = tid >> 4;   // 0..15 row group
    const int tc = tid & 15;   // 0..15 col group
    float acc[4][4] = {};

    for (int k0 = 0; k0 < K; k0 += 16) {
        #pragma unroll
        for (int t = 0; t < 4; t++) {
            int i = tid + t * 256;           // 0..1023
            int kk = i & 15, mm = i >> 4;    // 16 consecutive k per row -> 64B segments
            int gm = bm + mm, gk = k0 + kk;
            As[kk][mm] = (gm < M && gk < K) ? A[(size_t)gm * K + gk] : 0.f;
        }
        #pragma unroll
        for (int t = 0; t < 4; t++) {
            int i = tid + t * 256;
            int kk = i >> 6, nn = i & 63;    // 64 consecutive n -> 256B coalesced
            int gk = k0 + kk, gn = bn + nn;
            Bs[kk][nn] = (gk < K && gn < N) ? B[(size_t)gk * N + gn] : 0.f;
        }
        __syncthreads();
        #pragma unroll
        for (int kk = 0; kk < 16; kk++) {
            float a[4], b[4];
            #pragma unroll
            for (int i = 0; i < 4; i++) a[i] = As[kk][tr * 4 + i];
            #pragma unroll
            for (int j = 0; j < 4; j++) b[j] = Bs[kk][tc * 4 + j];
            #pragma unroll
            for (int i = 0; i < 4; i++)
                #pragma unroll
                for (int j = 0; j < 4; j++) acc[i][j] += a[i] * b[j];
        }
        __syncthreads();
    }

    #pragma unroll
    for (int i = 0; i < 4; i++) {
        int gm = bm + tr * 4 + i;
        if (gm >= M) continue;
        #pragma unroll
        for (int j = 0; j < 4; j++) {
            int gn = bn + tc * 4 + j;
            if (gn < N) C[(size_t)gm * N + gn] = acc[i][j];
        }
    }
}

// ---------------- SpMM (CSR by dst), one wave per dst row ----------------

template <int F, int NCH, bool RELU>
__global__ __launch_bounds__(256) void spmm_kernel(const int* __restrict__ row_ptr,
                                                   const int* __restrict__ csr_src,
                                                   const float* __restrict__ csr_w,
                                                   const float* __restrict__ support,
                                                   const float* __restrict__ bias,
                                                   float* __restrict__ out, int N) {
    int wave = blockIdx.x * (blockDim.x >> 6) + (threadIdx.x >> 6);
    int lane = threadIdx.x & 63;
    if (wave >= N) return;
    int beg = row_ptr[wave], end = row_ptr[wave + 1];
    float acc[NCH] = {};
    for (int e = beg; e < end; e++) {
        int s = csr_src[e];
        float w = csr_w[e];
        const float* sp = support + (size_t)s * F;
        #pragma unroll
        for (int j = 0; j < NCH; j++) {
            int f = j * 64 + lane;
            if (f < F) acc[j] += w * sp[f];
        }
    }
    #pragma unroll
    for (int j = 0; j < NCH; j++) {
        int f = j * 64 + lane;
        if (f < F) {
            float v = acc[j] + bias[f];
            out[(size_t)wave * F + f] = RELU ? fmaxf(v, 0.f) : v;
        }
    }
}

// layer 3: aggregation + bias + softmax fused; F = 40 (<= 64 lanes)
__global__ __launch_bounds__(256) void spmm_softmax_kernel(const int* __restrict__ row_ptr,
                                                           const int* __restrict__ csr_src,
                                                           const float* __restrict__ csr_w,
                                                           const float* __restrict__ support,
                                                           const float* __restrict__ bias,
                                                           float* __restrict__ out, int N) {
    int wave = blockIdx.x * (blockDim.x >> 6) + (threadIdx.x >> 6);
    int lane = threadIdx.x & 63;
    if (wave >= N) return;
    int beg = row_ptr[wave], end = row_ptr[wave + 1];
    float acc = 0.f;
    for (int e = beg; e < end; e++) {
        int s = csr_src[e];
        float w = csr_w[e];
        if (lane < NCLASS) acc += w * support[(size_t)s * NCLASS + lane];
    }
    float v = (lane < NCLASS) ? acc + bias[lane] : -INFINITY;
    float m = v;
    #pragma unroll
    for (int off = 32; off; off >>= 1) m = fmaxf(m, __shfl_xor(m, off));
    float ex = (lane < NCLASS) ? expf(v - m) : 0.f;
    float s = ex;
    #pragma unroll
    for (int off = 32; off; off >>= 1) s += __shfl_xor(s, off);
    if (lane < NCLASS) out[(size_t)wave * NCLASS + lane] = ex / s;
}

// ---------------- launch ----------------

extern "C" void kernel_launch(void* const* d_in, const int* in_sizes, int n_in,
                              void* d_out, int out_size, void* d_ws, size_t ws_size,
                              hipStream_t stream) {
    const float* x   = (const float*)d_in[0];
    const int*   ei  = (const int*)d_in[1];
    const float* ew  = (const float*)d_in[2];
    const float* w1  = (const float*)d_in[3];
    const float* b1  = (const float*)d_in[4];
    const float* w2  = (const float*)d_in[5];
    const float* b2  = (const float*)d_in[6];
    const float* w3  = (const float*)d_in[7];
    const float* b3  = (const float*)d_in[8];
    float* out = (float*)d_out;

    const int N = in_sizes[0] / NFEAT;   // 100000
    const int E = in_sizes[2];           // 3200000
    const int* src = ei;
    const int* dst = ei + E;

    // workspace layout
    char* p = (char*)d_ws;
    auto alloc = [&](size_t bytes) {
        void* r = (void*)p;
        p += (bytes + 255) & ~(size_t)255;
        return r;
    };
    int*   counts  = (int*)alloc((size_t)N * 4);
    int*   row_ptr = (int*)alloc((size_t)(N + 1) * 4);
    int*   nextp   = (int*)alloc((size_t)N * 4);
    int*   csr_src = (int*)alloc((size_t)E * 4);
    float* csr_w   = (float*)alloc((size_t)E * 4);
    float* bufA    = (float*)alloc((size_t)N * H1 * 4);  // supports
    float* bufB    = (float*)alloc((size_t)N * H1 * 4);  // h1 / h2

    // ---- CSR build ----
    hipMemsetAsync(counts, 0, (size_t)N * 4, stream);
    count_dst_kernel<<<(E + 255) / 256, 256, 0, stream>>>(dst, counts, E);
    scan_kernel<<<1, 1024, 0, stream>>>(counts, row_ptr, N);
    hipMemcpyAsync(nextp, row_ptr, (size_t)N * 4, hipMemcpyDeviceToDevice, stream);
    fill_csr_kernel<<<(E + 255) / 256, 256, 0, stream>>>(src, dst, ew, nextp, csr_src, csr_w, E);

    const int mtiles = (N + 63) / 64;
    const int wgs = (N + 3) / 4;  // 4 waves per block in spmm

    // ---- layer 1: support1 = x @ w1 (bufA); h1 = relu(Agg + b1) (bufB) ----
    gemm_f32_kernel<<<dim3((H1 + 63) / 64, mtiles), 256, 0, stream>>>(x, w1, bufA, N, H1, NFEAT);
    spmm_kernel<H1, 5, true><<<wgs, 256, 0, stream>>>(row_ptr, csr_src, csr_w, bufA, b1, bufB, N);

    // ---- layer 2: support2 = h1 @ w2 (bufA); h2 = relu(Agg + b2) (bufB) ----
    gemm_f32_kernel<<<dim3((H2 + 63) / 64, mtiles), 256, 0, stream>>>(bufB, w2, bufA, N, H2, H1);
    spmm_kernel<H2, 4, true><<<wgs, 256, 0, stream>>>(row_ptr, csr_src, csr_w, bufA, b2, bufB, N);

    // ---- layer 3: support3 = h2 @ w3 (bufA); out = softmax(Agg + b3) ----
    gemm_f32_kernel<<<dim3((NCLASS + 63) / 64, mtiles), 256, 0, stream>>>(bufB, w3, bufA, N, NCLASS, H2);
    spmm_softmax_kernel<<<wgs, 256, 0, stream>>>(row_ptr, csr_src, csr_w, bufA, b3, out, N);
}

// Round 2
// 2493.243 us; speedup vs baseline: 1.2755x; 1.2755x over previous
//
#include <hip/hip_runtime.h>
#include <hip/hip_bf16.h>
#include <math.h>

#define NFEAT 512
#define H1 300
#define H2 200
#define NCLASS 40

typedef __attribute__((ext_vector_type(8))) short short8;
typedef __attribute__((ext_vector_type(4))) float f32x4;

__device__ __forceinline__ void stage16(const void* gptr, void* ldsptr) {
    // 16B per lane; LDS dest = wave-uniform base + lane*16
    __builtin_amdgcn_global_load_lds(
        (const __attribute__((address_space(1))) unsigned int*)gptr,
        (__attribute__((address_space(3))) unsigned int*)ldsptr,
        16, 0, 0);
}

// ---------------- CSR construction ----------------

__global__ __launch_bounds__(256) void count_dst_kernel(const int* __restrict__ dst,
                                                        int* __restrict__ counts, int E) {
    int i = blockIdx.x * blockDim.x + threadIdx.x;
    if (i < E) atomicAdd(&counts[dst[i]], 1);
}

__global__ __launch_bounds__(1024) void scan_kernel(const int* __restrict__ counts,
                                                    int* __restrict__ row_ptr, int N) {
    __shared__ int sdata[1024];
    __shared__ int carry_s;
    int tid = threadIdx.x;
    if (tid == 0) { carry_s = 0; row_ptr[0] = 0; }
    __syncthreads();
    for (int base = 0; base < N; base += 1024) {
        int i = base + tid;
        int v = (i < N) ? counts[i] : 0;
        sdata[tid] = v;
        __syncthreads();
        #pragma unroll
        for (int off = 1; off < 1024; off <<= 1) {
            int t = (tid >= off) ? sdata[tid - off] : 0;
            __syncthreads();
            sdata[tid] += t;
            __syncthreads();
        }
        int carry = carry_s;
        if (i < N) row_ptr[i + 1] = sdata[tid] + carry;
        __syncthreads();
        if (tid == 1023) carry_s = carry + sdata[1023];
        __syncthreads();
    }
}

__global__ __launch_bounds__(256) void fill_csr_kernel(const int* __restrict__ src,
                                                       const int* __restrict__ dst,
                                                       const float* __restrict__ ew,
                                                       int* __restrict__ next,
                                                       int* __restrict__ csr_src,
                                                       float* __restrict__ csr_w, int E) {
    int i = blockIdx.x * blockDim.x + threadIdx.x;
    if (i < E) {
        int d = dst[i];
        int pos = atomicAdd(&next[d], 1);
        csr_src[pos] = src[i];
        csr_w[pos]   = ew[i];
    }
}

// ---------------- fp32 -> bf16 hi/lo split ----------------

__global__ __launch_bounds__(256) void split_f32_kernel(const float* __restrict__ in,
                                                        __hip_bfloat16* __restrict__ hi,
                                                        __hip_bfloat16* __restrict__ lo,
                                                        size_t n) {
    size_t i = (size_t)blockIdx.x * 256 + threadIdx.x;
    if (i < n) {
        float a = in[i];
        __hip_bfloat16 h = __float2bfloat16(a);
        hi[i] = h;
        lo[i] = __float2bfloat16(a - __bfloat162float(h));
    }
}

// w [K][N] fp32 -> wt hi/lo [NPAD][KPAD] bf16 (transpose + zero-pad)
__global__ __launch_bounds__(256) void split_wt_kernel(const float* __restrict__ w,
                                                       __hip_bfloat16* __restrict__ hi,
                                                       __hip_bfloat16* __restrict__ lo,
                                                       int K, int N, int KPAD, int NPAD) {
    int i = blockIdx.x * 256 + threadIdx.x;
    if (i >= NPAD * KPAD) return;
    int n = i / KPAD, k = i - n * KPAD;
    float a = (n < N && k < K) ? w[(size_t)k * N + n] : 0.f;
    __hip_bfloat16 h = __float2bfloat16(a);
    hi[i] = h;
    lo[i] = __float2bfloat16(a - __bfloat162float(h));
}

// ---------------- split-bf16 MFMA GEMM ----------------
// C[M x Nreal] fp32 = (Ahi+Alo)[M x KPAD] @ (Bhi+Blo)^T  (B stored [NPAD][KPAD])
// block: 256 thr = 4 waves, tile 256x64, BK=64, each wave 64x64 via 4x4 16x16x32 frags.
// 3 MFMA passes: hi*hi + hi*lo + lo*hi (fp32 accumulate) ~= fp32 precision.

template <int KPAD>
__global__ __launch_bounds__(256, 2) void gemm_mfma_kernel(
        const __hip_bfloat16* __restrict__ Ahi_, const __hip_bfloat16* __restrict__ Alo_,
        const __hip_bfloat16* __restrict__ Bhi_, const __hip_bfloat16* __restrict__ Blo_,
        float* __restrict__ C, int M, int Nreal) {
    extern __shared__ short lds[];
    short* As_hi = lds;               // 256*64 = 16384 shorts
    short* As_lo = lds + 16384;
    short* Bs_hi = lds + 32768;       // 64*64 = 4096
    short* Bs_lo = lds + 36864;       // total 40960 shorts = 80 KB

    const short* Ahi = (const short*)Ahi_;
    const short* Alo = (const short*)Alo_;
    const short* Bhi = (const short*)Bhi_;
    const short* Blo = (const short*)Blo_;

    const int tid = threadIdx.x;
    const int wave = tid >> 6, lane = tid & 63;
    const int lm = lane & 15, quad = lane >> 4;
    const int bm = blockIdx.y * 256, bn = blockIdx.x * 64;

    f32x4 acc[4][4] = {};

    for (int k0 = 0; k0 < KPAD; k0 += 64) {
        // ---- stage A tile 256x64 hi+lo (swizzled: chunk c stored at c^(m&7)) ----
        #pragma unroll
        for (int i = 0; i < 8; i++) {
            int t = i * 256 + tid;                 // slot 0..2047
            int m = t >> 3;
            int c = (t & 7) ^ (m & 7);             // global k-chunk for this slot
            int row = bm + m; row = row < M ? row : M - 1;
            size_t goff = (size_t)row * KPAD + (size_t)(k0 + c * 8);
            int lbase = (i * 256 + wave * 64) * 8; // wave-uniform LDS base (elems)
            stage16(Ahi + goff, As_hi + lbase);
            stage16(Alo + goff, As_lo + lbase);
        }
        // ---- stage B tile 64x64 hi+lo ----
        #pragma unroll
        for (int i = 0; i < 2; i++) {
            int t = i * 256 + tid;                 // slot 0..511
            int n = t >> 3;
            int c = (t & 7) ^ (n & 7);
            size_t goff = (size_t)(bn + n) * KPAD + (size_t)(k0 + c * 8);
            int lbase = (i * 256 + wave * 64) * 8;
            stage16(Bhi + goff, Bs_hi + lbase);
            stage16(Blo + goff, Bs_lo + lbase);
        }
        __syncthreads();

        #pragma unroll
        for (int h = 0; h < 2; h++) {
            const int cidx = h * 4 + quad;         // k-chunk this lane reads
            short8 ah[4], al[4], bh[4], bl[4];
            #pragma unroll
            for (int i = 0; i < 4; i++) {
                int m = wave * 64 + i * 16 + lm;
                int off = (m * 8 + (cidx ^ (m & 7))) * 8;
                ah[i] = *(const short8*)(As_hi + off);
                al[i] = *(const short8*)(As_lo + off);
            }
            #pragma unroll
            for (int j = 0; j < 4; j++) {
                int n = j * 16 + lm;
                int off = (n * 8 + (cidx ^ (n & 7))) * 8;
                bh[j] = *(const short8*)(Bs_hi + off);
                bl[j] = *(const short8*)(Bs_lo + off);
            }
            #pragma unroll
            for (int i = 0; i < 4; i++)
                #pragma unroll
                for (int j = 0; j < 4; j++) {
                    acc[i][j] = __builtin_amdgcn_mfma_f32_16x16x32_bf16(ah[i], bh[j], acc[i][j], 0, 0, 0);
                    acc[i][j] = __builtin_amdgcn_mfma_f32_16x16x32_bf16(ah[i], bl[j], acc[i][j], 0, 0, 0);
                    acc[i][j] = __builtin_amdgcn_mfma_f32_16x16x32_bf16(al[i], bh[j], acc[i][j], 0, 0, 0);
                }
        }
        __syncthreads();
    }

    // epilogue: D row = quad*4+r, col = lm within each 16x16 frag
    #pragma unroll
    for (int i = 0; i < 4; i++) {
        #pragma unroll
        for (int j = 0; j < 4; j++) {
            #pragma unroll
            for (int r = 0; r < 4; r++) {
                int row = bm + wave * 64 + i * 16 + quad * 4 + r;
                int col = bn + j * 16 + lm;
                if (row < M && col < Nreal)
                    C[(size_t)row * Nreal + col] = acc[i][j][r];
            }
        }
    }
}

// ---------------- SpMM (CSR by dst), one wave per dst row ----------------
// epilogue writes relu result as bf16 hi/lo pair, row stride NCH*64 (zero-padded)

template <int F, int NCH>
__global__ __launch_bounds__(256) void spmm_relu_split_kernel(
        const int* __restrict__ row_ptr, const int* __restrict__ csr_src,
        const float* __restrict__ csr_w, const float* __restrict__ support,
        const float* __restrict__ bias,
        __hip_bfloat16* __restrict__ outhi, __hip_bfloat16* __restrict__ outlo, int N) {
    int wave = blockIdx.x * (blockDim.x >> 6) + (threadIdx.x >> 6);
    int lane = threadIdx.x & 63;
    if (wave >= N) return;
    int beg = row_ptr[wave], end = row_ptr[wave + 1];
    float acc[NCH] = {};
    for (int e = beg; e < end; e++) {
        int s = csr_src[e];
        float w = csr_w[e];
        const float* sp = support + (size_t)s * F;
        #pragma unroll
        for (int j = 0; j < NCH; j++) {
            int f = j * 64 + lane;
            if (f < F) acc[j] += w * sp[f];
        }
    }
    #pragma unroll
    for (int j = 0; j < NCH; j++) {
        int f = j * 64 + lane;                       // f < NCH*64 always
        float v = (f < F) ? fmaxf(acc[j] + bias[f], 0.f) : 0.f;
        __hip_bfloat16 h = __float2bfloat16(v);
        size_t o = (size_t)wave * (NCH * 64) + f;
        outhi[o] = h;
        outlo[o] = __float2bfloat16(v - __bfloat162float(h));
    }
}

// layer 3: aggregation + bias + softmax fused; F = 40 (<= 64 lanes)
__global__ __launch_bounds__(256) void spmm_softmax_kernel(const int* __restrict__ row_ptr,
                                                           const int* __restrict__ csr_src,
                                                           const float* __restrict__ csr_w,
                                                           const float* __restrict__ support,
                                                           const float* __restrict__ bias,
                                                           float* __restrict__ out, int N) {
    int wave = blockIdx.x * (blockDim.x >> 6) + (threadIdx.x >> 6);
    int lane = threadIdx.x & 63;
    if (wave >= N) return;
    int beg = row_ptr[wave], end = row_ptr[wave + 1];
    float acc = 0.f;
    for (int e = beg; e < end; e++) {
        int s = csr_src[e];
        float w = csr_w[e];
        if (lane < NCLASS) acc += w * support[(size_t)s * NCLASS + lane];
    }
    float v = (lane < NCLASS) ? acc + bias[lane] : -INFINITY;
    float m = v;
    #pragma unroll
    for (int off = 32; off; off >>= 1) m = fmaxf(m, __shfl_xor(m, off));
    float ex = (lane < NCLASS) ? expf(v - m) : 0.f;
    float s = ex;
    #pragma unroll
    for (int off = 32; off; off >>= 1) s += __shfl_xor(s, off);
    if (lane < NCLASS) out[(size_t)wave * NCLASS + lane] = ex / s;
}

// ---------------- launch ----------------

extern "C" void kernel_launch(void* const* d_in, const int* in_sizes, int n_in,
                              void* d_out, int out_size, void* d_ws, size_t ws_size,
                              hipStream_t stream) {
    const float* x   = (const float*)d_in[0];
    const int*   ei  = (const int*)d_in[1];
    const float* ew  = (const float*)d_in[2];
    const float* w1  = (const float*)d_in[3];
    const float* b1  = (const float*)d_in[4];
    const float* w2  = (const float*)d_in[5];
    const float* b2  = (const float*)d_in[6];
    const float* w3  = (const float*)d_in[7];
    const float* b3  = (const float*)d_in[8];
    float* out = (float*)d_out;

    const int N = in_sizes[0] / NFEAT;   // 100000
    const int E = in_sizes[2];           // 3200000
    const int* src = ei;
    const int* dst = ei + E;

    // padded dims (multiples of 64 in K, 64 in N-tiles)
    const int KP1 = 512, NP1 = 320;      // layer1: K=512, N=300
    const int KP2 = 320, NP2 = 256;      // layer2: K=300, N=200
    const int KP3 = 256, NP3 = 64;       // layer3: K=200, N=40

    char* base = (char*)d_ws;
    // Region R1 (0 .. ~205MB): first holds XHI/XLO; after gemm1, reused for CSR + H buffers
    const size_t R1 = 0;
    __hip_bfloat16* XHI = (__hip_bfloat16*)(base + R1);                       // 102,400,000 B
    __hip_bfloat16* XLO = (__hip_bfloat16*)(base + R1 + 102400000);           // 102,400,000 B
    // overlay (after gemm1):
    int*   counts  = (int*)(base + R1 + 0);             // 400,000
    int*   row_ptr = (int*)(base + R1 + 400128);        // 400,004
    int*   nextp   = (int*)(base + R1 + 800384);        // 400,000
    int*   csr_src = (int*)(base + R1 + 1200640);       // 12,800,000
    float* csr_w   = (float*)(base + R1 + 14000640);    // 12,800,000
    __hip_bfloat16* H1HI = (__hip_bfloat16*)(base + R1 + 27200512);  // 100000*320*2 = 64,000,000
    __hip_bfloat16* H1LO = (__hip_bfloat16*)(base + R1 + 91200512);  // 64,000,000 -> ends 155.2MB
    __hip_bfloat16* H2HI = (__hip_bfloat16*)(base + R1 + 27200512);  // reuse H1 region after gemm2
    __hip_bfloat16* H2LO = (__hip_bfloat16*)(base + R1 + 78400512);  // 100000*256*2 = 51,200,000

    // Region R2: support fp32 (max 100000*300*4 = 120MB)
    const size_t R2 = 205000704;
    float* support = (float*)(base + R2);

    // Region R3: weight buffers (bf16 hi/lo, transposed+padded)
    size_t wo = R2 + 120000256;
    auto walloc = [&](size_t bytes) { void* r = base + wo; wo += (bytes + 255) & ~(size_t)255; return r; };
    __hip_bfloat16* W1HI = (__hip_bfloat16*)walloc((size_t)NP1 * KP1 * 2);
    __hip_bfloat16* W1LO = (__hip_bfloat16*)walloc((size_t)NP1 * KP1 * 2);
    __hip_bfloat16* W2HI = (__hip_bfloat16*)walloc((size_t)NP2 * KP2 * 2);
    __hip_bfloat16* W2LO = (__hip_bfloat16*)walloc((size_t)NP2 * KP2 * 2);
    __hip_bfloat16* W3HI = (__hip_bfloat16*)walloc((size_t)NP3 * KP3 * 2);
    __hip_bfloat16* W3LO = (__hip_bfloat16*)walloc((size_t)NP3 * KP3 * 2);

    const int LDS_BYTES = 80 * 1024;
    const int mtiles = (N + 255) / 256;          // 391
    const int wgs = (N + 3) / 4;                 // spmm: 4 waves/block

    // ---- input conversions ----
    {
        size_t nx = (size_t)N * NFEAT;
        split_f32_kernel<<<(int)((nx + 255) / 256), 256, 0, stream>>>(x, XHI, XLO, nx);
    }
    split_wt_kernel<<<(NP1 * KP1 + 255) / 256, 256, 0, stream>>>(w1, W1HI, W1LO, NFEAT, H1, KP1, NP1);
    split_wt_kernel<<<(NP2 * KP2 + 255) / 256, 256, 0, stream>>>(w2, W2HI, W2LO, H1, H2, KP2, NP2);
    split_wt_kernel<<<(NP3 * KP3 + 255) / 256, 256, 0, stream>>>(w3, W3HI, W3LO, H2, NCLASS, KP3, NP3);

    // ---- layer 1 GEMM: support = X @ W1 ----
    gemm_mfma_kernel<KP1><<<dim3(NP1 / 64, mtiles), 256, LDS_BYTES, stream>>>(
        XHI, XLO, W1HI, W1LO, support, N, H1);

    // ---- CSR build (overlays X region; X dead after gemm1) ----
    hipMemsetAsync(counts, 0, (size_t)N * 4, stream);
    count_dst_kernel<<<(E + 255) / 256, 256, 0, stream>>>(dst, counts, E);
    scan_kernel<<<1, 1024, 0, stream>>>(counts, row_ptr, N);
    hipMemcpyAsync(nextp, row_ptr, (size_t)N * 4, hipMemcpyDeviceToDevice, stream);
    fill_csr_kernel<<<(E + 255) / 256, 256, 0, stream>>>(src, dst, ew, nextp, csr_src, csr_w, E);

    // ---- layer 1 SpMM + relu -> H1 (bf16 hi/lo, stride 320) ----
    spmm_relu_split_kernel<H1, 5><<<wgs, 256, 0, stream>>>(row_ptr, csr_src, csr_w, support, b1, H1HI, H1LO, N);

    // ---- layer 2 ----
    gemm_mfma_kernel<KP2><<<dim3(NP2 / 64, mtiles), 256, LDS_BYTES, stream>>>(
        H1HI, H1LO, W2HI, W2LO, support, N, H2);
    spmm_relu_split_kernel<H2, 4><<<wgs, 256, 0, stream>>>(row_ptr, csr_src, csr_w, support, b2, H2HI, H2LO, N);

    // ---- layer 3 ----
    gemm_mfma_kernel<KP3><<<dim3(NP3 / 64, mtiles), 256, LDS_BYTES, stream>>>(
        H2HI, H2LO, W3HI, W3LO, support, N, NCLASS);
    spmm_softmax_kernel<<<wgs, 256, 0, stream>>>(row_ptr, csr_src, csr_w, support, b3, out, N);
}

// Round 4
// 2017.885 us; speedup vs baseline: 1.5759x; 1.2356x over previous
//
#include <hip/hip_runtime.h>
#include <hip/hip_bf16.h>
#include <hip/hip_fp16.h>
#include <math.h>

#define NFEAT 512
#define H1 300
#define H2 200
#define NCLASS 40

typedef __attribute__((ext_vector_type(8))) short short8;
typedef __attribute__((ext_vector_type(4))) float f32x4;
typedef __attribute__((ext_vector_type(2))) unsigned int u32x2;

__device__ __forceinline__ void stage16(const void* gptr, void* ldsptr) {
    __builtin_amdgcn_global_load_lds(
        (const __attribute__((address_space(1))) unsigned int*)gptr,
        (__attribute__((address_space(3))) unsigned int*)ldsptr,
        16, 0, 0);
}

__device__ __forceinline__ unsigned short f2bf(float f) {
    __hip_bfloat16 h = __float2bfloat16(f);
    return *reinterpret_cast<unsigned short*>(&h);
}
__device__ __forceinline__ float bfbits2f(unsigned int b) {
    return __uint_as_float(b << 16);
}
__device__ __forceinline__ float2 h2f2(unsigned int u) {
    __half2 h = *reinterpret_cast<__half2*>(&u);
    return __half22float2(h);
}

// ---------------- CSR construction ----------------

__global__ __launch_bounds__(256) void count_dst_kernel(const int* __restrict__ dst,
                                                        int* __restrict__ counts, int E) {
    int i = blockIdx.x * blockDim.x + threadIdx.x;
    if (i < E) atomicAdd(&counts[dst[i]], 1);
}

// serial-per-thread + one block scan (few barriers)
__global__ __launch_bounds__(1024) void scan_kernel(const int* __restrict__ counts,
                                                    int* __restrict__ row_ptr, int N) {
    __shared__ int sums[1024];
    const int tid = threadIdx.x;
    const int CH = (N + 1023) >> 10;
    const int b = tid * CH;
    const int e = min(b + CH, N);
    int s = 0;
    for (int i = b; i < e; i++) s += counts[i];
    sums[tid] = s;
    __syncthreads();
    #pragma unroll
    for (int off = 1; off < 1024; off <<= 1) {
        int t = (tid >= off) ? sums[tid - off] : 0;
        __syncthreads();
        sums[tid] += t;
        __syncthreads();
    }
    int run = (tid > 0) ? sums[tid - 1] : 0;
    for (int i = b; i < e; i++) {
        row_ptr[i] = run;
        run += counts[i];
    }
    if (tid == 0) row_ptr[N] = sums[1023];
}

__global__ __launch_bounds__(256) void fill_csr_kernel(const int* __restrict__ src,
                                                       const int* __restrict__ dst,
                                                       const float* __restrict__ ew,
                                                       int* __restrict__ next,
                                                       int2* __restrict__ csr_sw, int E) {
    int i = blockIdx.x * blockDim.x + threadIdx.x;
    if (i < E) {
        int d = dst[i];
        int pos = atomicAdd(&next[d], 1);
        csr_sw[pos] = make_int2(src[i], __float_as_int(ew[i]));
    }
}

// ---------------- fp32 -> bf16 hi/lo split ----------------

__global__ __launch_bounds__(256) void split_f32_kernel(const float* __restrict__ in,
                                                        unsigned short* __restrict__ hi,
                                                        unsigned short* __restrict__ lo,
                                                        size_t n) {
    size_t i = (size_t)blockIdx.x * 256 + threadIdx.x;
    if (i < n) {
        float a = in[i];
        unsigned short h = f2bf(a);
        hi[i] = h;
        lo[i] = f2bf(a - bfbits2f(h));
    }
}

// w [K][N] fp32 -> wt hi/lo [NPAD][KPAD] bf16 (transpose + zero-pad)
__global__ __launch_bounds__(256) void split_wt_kernel(const float* __restrict__ w,
                                                       unsigned short* __restrict__ hi,
                                                       unsigned short* __restrict__ lo,
                                                       int K, int N, int KPAD, int NPAD) {
    int i = blockIdx.x * 256 + threadIdx.x;
    if (i >= NPAD * KPAD) return;
    int n = i / KPAD, k = i - n * KPAD;
    float a = (n < N && k < K) ? w[(size_t)k * N + n] : 0.f;
    unsigned short h = f2bf(a);
    hi[i] = h;
    lo[i] = f2bf(a - bfbits2f(h));
}

// ---------------- split-bf16 MFMA GEMM, fp16 output ----------------
// C[M x NP] fp16 = (Ahi+Alo)[M x KPAD] @ (Bhi+Blo)^T  (B stored [NPAD][KPAD])

template <int KPAD>
__global__ __launch_bounds__(256, 2) void gemm_mfma_kernel(
        const unsigned short* __restrict__ Ahi, const unsigned short* __restrict__ Alo,
        const unsigned short* __restrict__ Bhi, const unsigned short* __restrict__ Blo,
        unsigned short* __restrict__ C, int M, int NP) {
    extern __shared__ short lds[];
    short* As_hi = lds;               // 256*64
    short* As_lo = lds + 16384;
    short* Bs_hi = lds + 32768;       // 64*64
    short* Bs_lo = lds + 36864;       // 80 KB total

    const int tid = threadIdx.x;
    const int wave = tid >> 6, lane = tid & 63;
    const int lm = lane & 15, quad = lane >> 4;
    const int bm = blockIdx.y * 256, bn = blockIdx.x * 64;

    f32x4 acc[4][4] = {};

    for (int k0 = 0; k0 < KPAD; k0 += 64) {
        #pragma unroll
        for (int i = 0; i < 8; i++) {
            int t = i * 256 + tid;
            int m = t >> 3;
            int c = (t & 7) ^ (m & 7);
            int row = bm + m; row = row < M ? row : M - 1;
            size_t goff = (size_t)row * KPAD + (size_t)(k0 + c * 8);
            int lbase = (i * 256 + wave * 64) * 8;
            stage16(Ahi + goff, As_hi + lbase);
            stage16(Alo + goff, As_lo + lbase);
        }
        #pragma unroll
        for (int i = 0; i < 2; i++) {
            int t = i * 256 + tid;
            int n = t >> 3;
            int c = (t & 7) ^ (n & 7);
            size_t goff = (size_t)(bn + n) * KPAD + (size_t)(k0 + c * 8);
            int lbase = (i * 256 + wave * 64) * 8;
            stage16(Bhi + goff, Bs_hi + lbase);
            stage16(Blo + goff, Bs_lo + lbase);
        }
        __syncthreads();

        #pragma unroll
        for (int h = 0; h < 2; h++) {
            const int cidx = h * 4 + quad;
            short8 ah[4], al[4], bh[4], bl[4];
            #pragma unroll
            for (int i = 0; i < 4; i++) {
                int m = wave * 64 + i * 16 + lm;
                int off = (m * 8 + (cidx ^ (m & 7))) * 8;
                ah[i] = *(const short8*)(As_hi + off);
                al[i] = *(const short8*)(As_lo + off);
            }
            #pragma unroll
            for (int j = 0; j < 4; j++) {
                int n = j * 16 + lm;
                int off = (n * 8 + (cidx ^ (n & 7))) * 8;
                bh[j] = *(const short8*)(Bs_hi + off);
                bl[j] = *(const short8*)(Bs_lo + off);
            }
            #pragma unroll
            for (int i = 0; i < 4; i++)
                #pragma unroll
                for (int j = 0; j < 4; j++) {
                    acc[i][j] = __builtin_amdgcn_mfma_f32_16x16x32_bf16(ah[i], bh[j], acc[i][j], 0, 0, 0);
                    acc[i][j] = __builtin_amdgcn_mfma_f32_16x16x32_bf16(ah[i], bl[j], acc[i][j], 0, 0, 0);
                    acc[i][j] = __builtin_amdgcn_mfma_f32_16x16x32_bf16(al[i], bh[j], acc[i][j], 0, 0, 0);
                }
        }
        __syncthreads();
    }

    #pragma unroll
    for (int i = 0; i < 4; i++) {
        #pragma unroll
        for (int j = 0; j < 4; j++) {
            #pragma unroll
            for (int r = 0; r < 4; r++) {
                int row = bm + wave * 64 + i * 16 + quad * 4 + r;
                int col = bn + j * 16 + lm;
                if (row < M)
                    C[(size_t)row * NP + col] = __half_as_ushort(__float2half(acc[i][j][r]));
            }
        }
    }
}

// ---------------- SpMM (CSR by dst), one wave per dst row, fp16 gather ----------------
// support rows: NP fp16 elems (stride); gathers u32x2 (4 fp16) per lane.
// writes relu result as bf16 hi/lo, row stride NP, zero-padded.

template <int F, int NP>
__global__ __launch_bounds__(256) void spmm_relu_split_kernel(
        const int* __restrict__ row_ptr, const int2* __restrict__ csr_sw,
        const unsigned short* __restrict__ support, const float* __restrict__ bias,
        unsigned short* __restrict__ outhi, unsigned short* __restrict__ outlo, int N) {
    constexpr int F4 = F / 4;             // real 4-elem groups
    constexpr int NP4 = NP / 4;           // padded groups
    constexpr int NCH = (F4 + 63) / 64;   // gather chunks
    constexpr int NCHW = (NP4 + 63) / 64; // write chunks (>= NCH)

    int wave = blockIdx.x * (blockDim.x >> 6) + (threadIdx.x >> 6);
    int lane = threadIdx.x & 63;
    if (wave >= N) return;
    int beg = row_ptr[wave], end = row_ptr[wave + 1];

    float acc[NCHW][4] = {};

    int e = beg;
    for (; e + 1 < end; e += 2) {
        int2 sw0 = csr_sw[e];
        int2 sw1 = csr_sw[e + 1];
        const unsigned short* sp0 = support + (size_t)sw0.x * NP;
        const unsigned short* sp1 = support + (size_t)sw1.x * NP;
        float w0 = __int_as_float(sw0.y), w1 = __int_as_float(sw1.y);
        u32x2 u0[NCH], u1[NCH];
        #pragma unroll
        for (int j = 0; j < NCH; j++) {
            int f4 = j * 64 + lane;
            if (f4 < F4) {
                u0[j] = *(const u32x2*)(sp0 + f4 * 4);
                u1[j] = *(const u32x2*)(sp1 + f4 * 4);
            }
        }
        #pragma unroll
        for (int j = 0; j < NCH; j++) {
            int f4 = j * 64 + lane;
            if (f4 < F4) {
                float2 a0 = h2f2(u0[j].x), a1 = h2f2(u0[j].y);
                float2 c0 = h2f2(u1[j].x), c1 = h2f2(u1[j].y);
                acc[j][0] += w0 * a0.x + w1 * c0.x;
                acc[j][1] += w0 * a0.y + w1 * c0.y;
                acc[j][2] += w0 * a1.x + w1 * c1.x;
                acc[j][3] += w0 * a1.y + w1 * c1.y;
            }
        }
    }
    if (e < end) {
        int2 sw0 = csr_sw[e];
        const unsigned short* sp0 = support + (size_t)sw0.x * NP;
        float w0 = __int_as_float(sw0.y);
        #pragma unroll
        for (int j = 0; j < NCH; j++) {
            int f4 = j * 64 + lane;
            if (f4 < F4) {
                u32x2 u = *(const u32x2*)(sp0 + f4 * 4);
                float2 a0 = h2f2(u.x), a1 = h2f2(u.y);
                acc[j][0] += w0 * a0.x;
                acc[j][1] += w0 * a0.y;
                acc[j][2] += w0 * a1.x;
                acc[j][3] += w0 * a1.y;
            }
        }
    }

    #pragma unroll
    for (int j = 0; j < NCHW; j++) {
        int f4 = j * 64 + lane;
        if (f4 < NP4) {
            float v[4];
            bool real = f4 < F4;
            float4 bb = real ? ((const float4*)bias)[f4] : make_float4(0, 0, 0, 0);
            v[0] = real ? fmaxf(acc[j][0] + bb.x, 0.f) : 0.f;
            v[1] = real ? fmaxf(acc[j][1] + bb.y, 0.f) : 0.f;
            v[2] = real ? fmaxf(acc[j][2] + bb.z, 0.f) : 0.f;
            v[3] = real ? fmaxf(acc[j][3] + bb.w, 0.f) : 0.f;
            unsigned short h[4], l[4];
            #pragma unroll
            for (int k = 0; k < 4; k++) {
                h[k] = f2bf(v[k]);
                l[k] = f2bf(v[k] - bfbits2f(h[k]));
            }
            size_t o = (size_t)wave * NP + f4 * 4;
            u32x2 hw, lw;
            hw.x = (unsigned)h[0] | ((unsigned)h[1] << 16);
            hw.y = (unsigned)h[2] | ((unsigned)h[3] << 16);
            lw.x = (unsigned)l[0] | ((unsigned)l[1] << 16);
            lw.y = (unsigned)l[2] | ((unsigned)l[3] << 16);
            *(u32x2*)(outhi + o) = hw;
            *(u32x2*)(outlo + o) = lw;
        }
    }
}

// layer 3: aggregation (F=40, stride 64 fp16) + bias + softmax fused
__global__ __launch_bounds__(256) void spmm_softmax_kernel(
        const int* __restrict__ row_ptr, const int2* __restrict__ csr_sw,
        const unsigned short* __restrict__ support, const float* __restrict__ bias,
        float* __restrict__ out, int N) {
    int wave = blockIdx.x * (blockDim.x >> 6) + (threadIdx.x >> 6);
    int lane = threadIdx.x & 63;
    if (wave >= N) return;
    int beg = row_ptr[wave], end = row_ptr[wave + 1];
    const bool act = lane < NCLASS / 4;   // 10 lanes
    float acc[4] = {0.f, 0.f, 0.f, 0.f};
    for (int e = beg; e < end; e++) {
        int2 sw = csr_sw[e];
        float w = __int_as_float(sw.y);
        if (act) {
            u32x2 u = *(const u32x2*)(support + (size_t)sw.x * 64 + lane * 4);
            float2 a0 = h2f2(u.x), a1 = h2f2(u.y);
            acc[0] += w * a0.x;
            acc[1] += w * a0.y;
            acc[2] += w * a1.x;
            acc[3] += w * a1.y;
        }
    }
    float v[4];
    float m = -INFINITY;
    if (act) {
        float4 bb = ((const float4*)bias)[lane];
        v[0] = acc[0] + bb.x; v[1] = acc[1] + bb.y;
        v[2] = acc[2] + bb.z; v[3] = acc[3] + bb.w;
        m = fmaxf(fmaxf(v[0], v[1]), fmaxf(v[2], v[3]));
    }
    #pragma unroll
    for (int off = 8; off; off >>= 1) m = fmaxf(m, __shfl_xor(m, off));
    float s = 0.f, ex[4];
    if (act) {
        #pragma unroll
        for (int k = 0; k < 4; k++) { ex[k] = expf(v[k] - m); s += ex[k]; }
    }
    #pragma unroll
    for (int off = 8; off; off >>= 1) s += __shfl_xor(s, off);
    if (act) {
        float inv = 1.f / s;
        float4 r = make_float4(ex[0] * inv, ex[1] * inv, ex[2] * inv, ex[3] * inv);
        ((float4*)(out + (size_t)wave * NCLASS))[lane] = r;
    }
}

// ---------------- launch ----------------

extern "C" void kernel_launch(void* const* d_in, const int* in_sizes, int n_in,
                              void* d_out, int out_size, void* d_ws, size_t ws_size,
                              hipStream_t stream) {
    const float* x   = (const float*)d_in[0];
    const int*   ei  = (const int*)d_in[1];
    const float* ew  = (const float*)d_in[2];
    const float* w1  = (const float*)d_in[3];
    const float* b1  = (const float*)d_in[4];
    const float* w2  = (const float*)d_in[5];
    const float* b2  = (const float*)d_in[6];
    const float* w3  = (const float*)d_in[7];
    const float* b3  = (const float*)d_in[8];
    float* out = (float*)d_out;

    const int N = in_sizes[0] / NFEAT;   // 100000
    const int E = in_sizes[2];           // 3200000
    const int* src = ei;
    const int* dst = ei + E;

    const int KP1 = 512, NP1 = 320;      // layer1: K=512, N=300
    const int KP2 = 320, NP2 = 256;      // layer2: K=300, N=200
    const int KP3 = 256, NP3 = 64;       // layer3: K=200, N=40

    char* base = (char*)d_ws;
    // Region A (0..204.8MB): XHI/XLO, overlaid by H buffers after GEMM1
    unsigned short* XHI = (unsigned short*)(base);
    unsigned short* XLO = (unsigned short*)(base + 102400000);
    unsigned short* H1HI = (unsigned short*)(base);                 // 64,000,000
    unsigned short* H1LO = (unsigned short*)(base + 64000000);      // 64,000,000
    unsigned short* H2HI = (unsigned short*)(base);                 // 51,200,000
    unsigned short* H2LO = (unsigned short*)(base + 51200000);      // 51,200,000

    // Region B: support fp16 (max 100000*320*2 = 64MB)
    unsigned short* support = (unsigned short*)(base + 204800000);

    // Region C: weights
    size_t wo = 204800000 + 64000256;
    auto walloc = [&](size_t bytes) { void* r = base + wo; wo += (bytes + 255) & ~(size_t)255; return r; };
    unsigned short* W1HI = (unsigned short*)walloc((size_t)NP1 * KP1 * 2);
    unsigned short* W1LO = (unsigned short*)walloc((size_t)NP1 * KP1 * 2);
    unsigned short* W2HI = (unsigned short*)walloc((size_t)NP2 * KP2 * 2);
    unsigned short* W2LO = (unsigned short*)walloc((size_t)NP2 * KP2 * 2);
    unsigned short* W3HI = (unsigned short*)walloc((size_t)NP3 * KP3 * 2);
    unsigned short* W3LO = (unsigned short*)walloc((size_t)NP3 * KP3 * 2);
    // Region D: CSR (never overlaid)
    int*  counts  = (int*)walloc((size_t)N * 4);
    int*  row_ptr = (int*)walloc((size_t)(N + 1) * 4);
    int*  nextp   = (int*)walloc((size_t)N * 4);
    int2* csr_sw  = (int2*)walloc((size_t)E * 8);

    const int LDS_BYTES = 80 * 1024;
    const int mtiles = (N + 255) / 256;
    const int wgs = (N + 3) / 4;

    // ---- CSR build ----
    hipMemsetAsync(counts, 0, (size_t)N * 4, stream);
    count_dst_kernel<<<(E + 255) / 256, 256, 0, stream>>>(dst, counts, E);
    scan_kernel<<<1, 1024, 0, stream>>>(counts, row_ptr, N);
    hipMemcpyAsync(nextp, row_ptr, (size_t)N * 4, hipMemcpyDeviceToDevice, stream);
    fill_csr_kernel<<<(E + 255) / 256, 256, 0, stream>>>(src, dst, ew, nextp, csr_sw, E);

    // ---- conversions ----
    {
        size_t nx = (size_t)N * NFEAT;
        split_f32_kernel<<<(int)((nx + 255) / 256), 256, 0, stream>>>(x, XHI, XLO, nx);
    }
    split_wt_kernel<<<(NP1 * KP1 + 255) / 256, 256, 0, stream>>>(w1, W1HI, W1LO, NFEAT, H1, KP1, NP1);
    split_wt_kernel<<<(NP2 * KP2 + 255) / 256, 256, 0, stream>>>(w2, W2HI, W2LO, H1, H2, KP2, NP2);
    split_wt_kernel<<<(NP3 * KP3 + 255) / 256, 256, 0, stream>>>(w3, W3HI, W3LO, H2, NCLASS, KP3, NP3);

    // ---- layer 1 ----
    gemm_mfma_kernel<KP1><<<dim3(NP1 / 64, mtiles), 256, LDS_BYTES, stream>>>(
        XHI, XLO, W1HI, W1LO, support, N, NP1);
    spmm_relu_split_kernel<H1, NP1><<<wgs, 256, 0, stream>>>(row_ptr, csr_sw, support, b1, H1HI, H1LO, N);

    // ---- layer 2 ----
    gemm_mfma_kernel<KP2><<<dim3(NP2 / 64, mtiles), 256, LDS_BYTES, stream>>>(
        H1HI, H1LO, W2HI, W2LO, support, N, NP2);
    spmm_relu_split_kernel<H2, NP2><<<wgs, 256, 0, stream>>>(row_ptr, csr_sw, support, b2, H2HI, H2LO, N);

    // ---- layer 3 ----
    gemm_mfma_kernel<KP3><<<dim3(NP3 / 64, mtiles), 256, LDS_BYTES, stream>>>(
        H2HI, H2LO, W3HI, W3LO, support, N, NP3);
    spmm_softmax_kernel<<<wgs, 256, 0, stream>>>(row_ptr, csr_sw, support, b3, out, N);
}

// Round 5
// 1807.194 us; speedup vs baseline: 1.7597x; 1.1166x over previous
//
#include <hip/hip_runtime.h>
#include <hip/hip_bf16.h>
#include <hip/hip_fp16.h>
#include <math.h>

#define NFEAT 512
#define H1 300
#define H2 200
#define NCLASS 40

typedef __attribute__((ext_vector_type(8))) short short8;
typedef __attribute__((ext_vector_type(4))) float f32x4;
typedef __attribute__((ext_vector_type(2))) unsigned int u32x2;

__device__ __forceinline__ void stage16(const void* gptr, void* ldsptr) {
    __builtin_amdgcn_global_load_lds(
        (const __attribute__((address_space(1))) unsigned int*)gptr,
        (__attribute__((address_space(3))) unsigned int*)ldsptr,
        16, 0, 0);
}

__device__ __forceinline__ unsigned short f2bf(float f) {
    __hip_bfloat16 h = __float2bfloat16(f);
    return *reinterpret_cast<unsigned short*>(&h);
}
__device__ __forceinline__ float bfbits2f(unsigned int b) {
    return __uint_as_float(b << 16);
}
__device__ __forceinline__ float2 h2f2(unsigned int u) {
    __half2 h = *reinterpret_cast<__half2*>(&u);
    return __half22float2(h);
}

// ---------------- CSR construction ----------------

__global__ __launch_bounds__(256) void count_dst_kernel(const int* __restrict__ dst,
                                                        int* __restrict__ counts, int E) {
    int i = blockIdx.x * blockDim.x + threadIdx.x;
    if (i < E) atomicAdd(&counts[dst[i]], 1);
}

// serial-per-thread + one block scan (few barriers)
__global__ __launch_bounds__(1024) void scan_kernel(const int* __restrict__ counts,
                                                    int* __restrict__ row_ptr, int N) {
    __shared__ int sums[1024];
    const int tid = threadIdx.x;
    const int CH = (N + 1023) >> 10;
    const int b = tid * CH;
    const int e = min(b + CH, N);
    int s = 0;
    for (int i = b; i < e; i++) s += counts[i];
    sums[tid] = s;
    __syncthreads();
    #pragma unroll
    for (int off = 1; off < 1024; off <<= 1) {
        int t = (tid >= off) ? sums[tid - off] : 0;
        __syncthreads();
        sums[tid] += t;
        __syncthreads();
    }
    int run = (tid > 0) ? sums[tid - 1] : 0;
    for (int i = b; i < e; i++) {
        row_ptr[i] = run;
        run += counts[i];
    }
    if (tid == 0) row_ptr[N] = sums[1023];
}

__global__ __launch_bounds__(256) void fill_csr_kernel(const int* __restrict__ src,
                                                       const int* __restrict__ dst,
                                                       const float* __restrict__ ew,
                                                       int* __restrict__ next,
                                                       int2* __restrict__ csr_sw, int E) {
    int i = blockIdx.x * blockDim.x + threadIdx.x;
    if (i < E) {
        int d = dst[i];
        int pos = atomicAdd(&next[d], 1);
        csr_sw[pos] = make_int2(src[i], __float_as_int(ew[i]));
    }
}

// ---------------- fp32 -> bf16 hi/lo split (vectorized, n % 4 == 0) ----------------

__global__ __launch_bounds__(256) void split_f32_kernel(const float* __restrict__ in,
                                                        unsigned short* __restrict__ hi,
                                                        unsigned short* __restrict__ lo,
                                                        size_t n4) {
    size_t i = (size_t)blockIdx.x * 256 + threadIdx.x;
    if (i < n4) {
        float4 a = ((const float4*)in)[i];
        unsigned short h[4], l[4];
        float v[4] = {a.x, a.y, a.z, a.w};
        #pragma unroll
        for (int k = 0; k < 4; k++) {
            h[k] = f2bf(v[k]);
            l[k] = f2bf(v[k] - bfbits2f(h[k]));
        }
        u32x2 hw, lw;
        hw.x = (unsigned)h[0] | ((unsigned)h[1] << 16);
        hw.y = (unsigned)h[2] | ((unsigned)h[3] << 16);
        lw.x = (unsigned)l[0] | ((unsigned)l[1] << 16);
        lw.y = (unsigned)l[2] | ((unsigned)l[3] << 16);
        *(u32x2*)(hi + i * 4) = hw;
        *(u32x2*)(lo + i * 4) = lw;
    }
}

// w [K][N] fp32 -> wt hi/lo [NPAD][KPAD] bf16 (transpose + zero-pad)
__global__ __launch_bounds__(256) void split_wt_kernel(const float* __restrict__ w,
                                                       unsigned short* __restrict__ hi,
                                                       unsigned short* __restrict__ lo,
                                                       int K, int N, int KPAD, int NPAD) {
    int i = blockIdx.x * 256 + threadIdx.x;
    if (i >= NPAD * KPAD) return;
    int n = i / KPAD, k = i - n * KPAD;
    float a = (n < N && k < K) ? w[(size_t)k * N + n] : 0.f;
    unsigned short h = f2bf(a);
    hi[i] = h;
    lo[i] = f2bf(a - bfbits2f(h));
}

// ---------------- split-bf16 MFMA GEMM, fp16 output ----------------
// C[M x NP] fp16 = (Ahi+Alo)[M x KPAD] @ (Bhi+Blo)^T  (B stored [NPAD][KPAD])
// 1D grid, XCD-aware swizzle: blocks sharing an M-tile have ids == x (mod 8)
// (same XCD under round-robin) and are temporally adjacent -> A-tile L2 reuse.

template <int KPAD, int NT>
__global__ __launch_bounds__(256, 2) void gemm_mfma_kernel(
        const unsigned short* __restrict__ Ahi, const unsigned short* __restrict__ Alo,
        const unsigned short* __restrict__ Bhi, const unsigned short* __restrict__ Blo,
        unsigned short* __restrict__ C, int M, int NP, int MT) {
    extern __shared__ short lds[];
    short* As_hi = lds;               // 256*64
    short* As_lo = lds + 16384;
    short* Bs_hi = lds + 32768;       // 64*64
    short* Bs_lo = lds + 36864;       // 80 KB total

    const int id = blockIdx.x;
    const int g  = id / (8 * NT);
    const int r  = id % (8 * NT);
    const int nt = r >> 3;
    const int x  = r & 7;
    const int mt = g * 8 + x;
    if (mt >= MT) return;

    const int tid = threadIdx.x;
    const int wave = tid >> 6, lane = tid & 63;
    const int lm = lane & 15, quad = lane >> 4;
    const int bm = mt * 256, bn = nt * 64;

    f32x4 acc[4][4] = {};

    for (int k0 = 0; k0 < KPAD; k0 += 64) {
        #pragma unroll
        for (int i = 0; i < 8; i++) {
            int t = i * 256 + tid;
            int m = t >> 3;
            int c = (t & 7) ^ (m & 7);
            int row = bm + m; row = row < M ? row : M - 1;
            size_t goff = (size_t)row * KPAD + (size_t)(k0 + c * 8);
            int lbase = (i * 256 + wave * 64) * 8;
            stage16(Ahi + goff, As_hi + lbase);
            stage16(Alo + goff, As_lo + lbase);
        }
        #pragma unroll
        for (int i = 0; i < 2; i++) {
            int t = i * 256 + tid;
            int n = t >> 3;
            int c = (t & 7) ^ (n & 7);
            size_t goff = (size_t)(bn + n) * KPAD + (size_t)(k0 + c * 8);
            int lbase = (i * 256 + wave * 64) * 8;
            stage16(Bhi + goff, Bs_hi + lbase);
            stage16(Blo + goff, Bs_lo + lbase);
        }
        __syncthreads();

        #pragma unroll
        for (int h = 0; h < 2; h++) {
            const int cidx = h * 4 + quad;
            short8 ah[4], al[4], bh[4], bl[4];
            #pragma unroll
            for (int i = 0; i < 4; i++) {
                int m = wave * 64 + i * 16 + lm;
                int off = (m * 8 + (cidx ^ (m & 7))) * 8;
                ah[i] = *(const short8*)(As_hi + off);
                al[i] = *(const short8*)(As_lo + off);
            }
            #pragma unroll
            for (int j = 0; j < 4; j++) {
                int n = j * 16 + lm;
                int off = (n * 8 + (cidx ^ (n & 7))) * 8;
                bh[j] = *(const short8*)(Bs_hi + off);
                bl[j] = *(const short8*)(Bs_lo + off);
            }
            #pragma unroll
            for (int i = 0; i < 4; i++)
                #pragma unroll
                for (int j = 0; j < 4; j++) {
                    acc[i][j] = __builtin_amdgcn_mfma_f32_16x16x32_bf16(ah[i], bh[j], acc[i][j], 0, 0, 0);
                    acc[i][j] = __builtin_amdgcn_mfma_f32_16x16x32_bf16(ah[i], bl[j], acc[i][j], 0, 0, 0);
                    acc[i][j] = __builtin_amdgcn_mfma_f32_16x16x32_bf16(al[i], bh[j], acc[i][j], 0, 0, 0);
                }
        }
        __syncthreads();
    }

    #pragma unroll
    for (int i = 0; i < 4; i++) {
        #pragma unroll
        for (int j = 0; j < 4; j++) {
            #pragma unroll
            for (int r2 = 0; r2 < 4; r2++) {
                int row = bm + wave * 64 + i * 16 + quad * 4 + r2;
                int col = bn + j * 16 + lm;
                if (row < M)
                    C[(size_t)row * NP + col] = __half_as_ushort(__float2half(acc[i][j][r2]));
            }
        }
    }
}

// ---------------- SpMM (CSR by dst), one wave per dst row, fp16 gather ----------------
// src/w are wave-uniform -> readfirstlane to SGPRs (saddr gathers, SALU row math).
// 4-edge unroll for memory-level parallelism.

template <int F, int NP>
__global__ __launch_bounds__(256) void spmm_relu_split_kernel(
        const int* __restrict__ row_ptr, const int2* __restrict__ csr_sw,
        const unsigned short* __restrict__ support, const float* __restrict__ bias,
        unsigned short* __restrict__ outhi, unsigned short* __restrict__ outlo, int N) {
    constexpr int F4 = F / 4;             // real 4-elem groups
    constexpr int NP4 = NP / 4;           // padded groups
    constexpr int NCH = (F4 + 63) / 64;   // gather chunks
    constexpr int NCHW = (NP4 + 63) / 64; // write chunks (>= NCH)

    int row = blockIdx.x * 4 + (threadIdx.x >> 6);
    int lane = threadIdx.x & 63;
    if (row >= N) return;
    int beg = row_ptr[row], end = row_ptr[row + 1];

    float acc[NCHW][4] = {};

    int e = beg;
    for (; e + 3 < end; e += 4) {
        int s_[4]; float w_[4];
        #pragma unroll
        for (int q = 0; q < 4; q++) {
            int2 sw = csr_sw[e + q];
            s_[q] = __builtin_amdgcn_readfirstlane(sw.x);
            w_[q] = __uint_as_float((unsigned)__builtin_amdgcn_readfirstlane(sw.y));
        }
        u32x2 u[4][NCH];
        #pragma unroll
        for (int q = 0; q < 4; q++) {
            const unsigned short* sp = support + (size_t)s_[q] * NP;
            #pragma unroll
            for (int j = 0; j < NCH; j++) {
                int f4 = j * 64 + lane;
                if (f4 < F4) u[q][j] = *(const u32x2*)(sp + f4 * 4);
            }
        }
        #pragma unroll
        for (int q = 0; q < 4; q++) {
            #pragma unroll
            for (int j = 0; j < NCH; j++) {
                int f4 = j * 64 + lane;
                if (f4 < F4) {
                    float2 a0 = h2f2(u[q][j].x), a1 = h2f2(u[q][j].y);
                    acc[j][0] += w_[q] * a0.x;
                    acc[j][1] += w_[q] * a0.y;
                    acc[j][2] += w_[q] * a1.x;
                    acc[j][3] += w_[q] * a1.y;
                }
            }
        }
    }
    for (; e < end; e++) {
        int2 sw = csr_sw[e];
        int ssrc = __builtin_amdgcn_readfirstlane(sw.x);
        float w0 = __uint_as_float((unsigned)__builtin_amdgcn_readfirstlane(sw.y));
        const unsigned short* sp = support + (size_t)ssrc * NP;
        #pragma unroll
        for (int j = 0; j < NCH; j++) {
            int f4 = j * 64 + lane;
            if (f4 < F4) {
                u32x2 u = *(const u32x2*)(sp + f4 * 4);
                float2 a0 = h2f2(u.x), a1 = h2f2(u.y);
                acc[j][0] += w0 * a0.x;
                acc[j][1] += w0 * a0.y;
                acc[j][2] += w0 * a1.x;
                acc[j][3] += w0 * a1.y;
            }
        }
    }

    #pragma unroll
    for (int j = 0; j < NCHW; j++) {
        int f4 = j * 64 + lane;
        if (f4 < NP4) {
            float v[4];
            bool real = f4 < F4;
            float4 bb = real ? ((const float4*)bias)[f4] : make_float4(0, 0, 0, 0);
            v[0] = real ? fmaxf(acc[j][0] + bb.x, 0.f) : 0.f;
            v[1] = real ? fmaxf(acc[j][1] + bb.y, 0.f) : 0.f;
            v[2] = real ? fmaxf(acc[j][2] + bb.z, 0.f) : 0.f;
            v[3] = real ? fmaxf(acc[j][3] + bb.w, 0.f) : 0.f;
            unsigned short h[4], l[4];
            #pragma unroll
            for (int k = 0; k < 4; k++) {
                h[k] = f2bf(v[k]);
                l[k] = f2bf(v[k] - bfbits2f(h[k]));
            }
            size_t o = (size_t)row * NP + f4 * 4;
            u32x2 hw, lw;
            hw.x = (unsigned)h[0] | ((unsigned)h[1] << 16);
            hw.y = (unsigned)h[2] | ((unsigned)h[3] << 16);
            lw.x = (unsigned)l[0] | ((unsigned)l[1] << 16);
            lw.y = (unsigned)l[2] | ((unsigned)l[3] << 16);
            *(u32x2*)(outhi + o) = hw;
            *(u32x2*)(outlo + o) = lw;
        }
    }
}

// layer 3: aggregation (F=40, stride 64 fp16) + bias + softmax fused
__global__ __launch_bounds__(256) void spmm_softmax_kernel(
        const int* __restrict__ row_ptr, const int2* __restrict__ csr_sw,
        const unsigned short* __restrict__ support, const float* __restrict__ bias,
        float* __restrict__ out, int N) {
    int row = blockIdx.x * 4 + (threadIdx.x >> 6);
    int lane = threadIdx.x & 63;
    if (row >= N) return;
    int beg = row_ptr[row], end = row_ptr[row + 1];
    const bool act = lane < NCLASS / 4;   // 10 lanes
    float acc[4] = {0.f, 0.f, 0.f, 0.f};
    int e = beg;
    for (; e + 1 < end; e += 2) {
        int2 sw0 = csr_sw[e];
        int2 sw1 = csr_sw[e + 1];
        int  s0 = __builtin_amdgcn_readfirstlane(sw0.x);
        int  s1 = __builtin_amdgcn_readfirstlane(sw1.x);
        float w0 = __uint_as_float((unsigned)__builtin_amdgcn_readfirstlane(sw0.y));
        float w1 = __uint_as_float((unsigned)__builtin_amdgcn_readfirstlane(sw1.y));
        if (act) {
            u32x2 u0 = *(const u32x2*)(support + (size_t)s0 * 64 + lane * 4);
            u32x2 u1 = *(const u32x2*)(support + (size_t)s1 * 64 + lane * 4);
            float2 a0 = h2f2(u0.x), a1 = h2f2(u0.y);
            float2 c0 = h2f2(u1.x), c1 = h2f2(u1.y);
            acc[0] += w0 * a0.x + w1 * c0.x;
            acc[1] += w0 * a0.y + w1 * c0.y;
            acc[2] += w0 * a1.x + w1 * c1.x;
            acc[3] += w0 * a1.y + w1 * c1.y;
        }
    }
    if (e < end) {
        int2 sw = csr_sw[e];
        int  s0 = __builtin_amdgcn_readfirstlane(sw.x);
        float w0 = __uint_as_float((unsigned)__builtin_amdgcn_readfirstlane(sw.y));
        if (act) {
            u32x2 u = *(const u32x2*)(support + (size_t)s0 * 64 + lane * 4);
            float2 a0 = h2f2(u.x), a1 = h2f2(u.y);
            acc[0] += w0 * a0.x;
            acc[1] += w0 * a0.y;
            acc[2] += w0 * a1.x;
            acc[3] += w0 * a1.y;
        }
    }
    float v[4];
    float m = -INFINITY;
    if (act) {
        float4 bb = ((const float4*)bias)[lane];
        v[0] = acc[0] + bb.x; v[1] = acc[1] + bb.y;
        v[2] = acc[2] + bb.z; v[3] = acc[3] + bb.w;
        m = fmaxf(fmaxf(v[0], v[1]), fmaxf(v[2], v[3]));
    }
    #pragma unroll
    for (int off = 8; off; off >>= 1) m = fmaxf(m, __shfl_xor(m, off));
    float s = 0.f, ex[4];
    if (act) {
        #pragma unroll
        for (int k = 0; k < 4; k++) { ex[k] = expf(v[k] - m); s += ex[k]; }
    }
    #pragma unroll
    for (int off = 8; off; off >>= 1) s += __shfl_xor(s, off);
    if (act) {
        float inv = 1.f / s;
        float4 r = make_float4(ex[0] * inv, ex[1] * inv, ex[2] * inv, ex[3] * inv);
        ((float4*)(out + (size_t)row * NCLASS))[lane] = r;
    }
}

// ---------------- launch ----------------

extern "C" void kernel_launch(void* const* d_in, const int* in_sizes, int n_in,
                              void* d_out, int out_size, void* d_ws, size_t ws_size,
                              hipStream_t stream) {
    const float* x   = (const float*)d_in[0];
    const int*   ei  = (const int*)d_in[1];
    const float* ew  = (const float*)d_in[2];
    const float* w1  = (const float*)d_in[3];
    const float* b1  = (const float*)d_in[4];
    const float* w2  = (const float*)d_in[5];
    const float* b2  = (const float*)d_in[6];
    const float* w3  = (const float*)d_in[7];
    const float* b3  = (const float*)d_in[8];
    float* out = (float*)d_out;

    const int N = in_sizes[0] / NFEAT;   // 100000
    const int E = in_sizes[2];           // 3200000
    const int* src = ei;
    const int* dst = ei + E;

    const int KP1 = 512, NP1 = 320, NT1 = 5;   // layer1: K=512, N=300
    const int KP2 = 320, NP2 = 256, NT2 = 4;   // layer2: K=300, N=200
    const int KP3 = 256, NP3 = 64,  NT3 = 1;   // layer3: K=200, N=40

    char* base = (char*)d_ws;
    // Region A (0..204.8MB): XHI/XLO, overlaid by H buffers after GEMM1
    unsigned short* XHI = (unsigned short*)(base);
    unsigned short* XLO = (unsigned short*)(base + 102400000);
    unsigned short* H1HI = (unsigned short*)(base);                 // 64,000,000
    unsigned short* H1LO = (unsigned short*)(base + 64000000);      // 64,000,000
    unsigned short* H2HI = (unsigned short*)(base);                 // 51,200,000
    unsigned short* H2LO = (unsigned short*)(base + 51200000);      // 51,200,000

    // Region B: support fp16 (max 100000*320*2 = 64MB)
    unsigned short* support = (unsigned short*)(base + 204800000);

    // Region C: weights
    size_t wo = 204800000 + 64000256;
    auto walloc = [&](size_t bytes) { void* r = base + wo; wo += (bytes + 255) & ~(size_t)255; return r; };
    unsigned short* W1HI = (unsigned short*)walloc((size_t)NP1 * KP1 * 2);
    unsigned short* W1LO = (unsigned short*)walloc((size_t)NP1 * KP1 * 2);
    unsigned short* W2HI = (unsigned short*)walloc((size_t)NP2 * KP2 * 2);
    unsigned short* W2LO = (unsigned short*)walloc((size_t)NP2 * KP2 * 2);
    unsigned short* W3HI = (unsigned short*)walloc((size_t)NP3 * KP3 * 2);
    unsigned short* W3LO = (unsigned short*)walloc((size_t)NP3 * KP3 * 2);
    // Region D: CSR (never overlaid)
    int*  counts  = (int*)walloc((size_t)N * 4);
    int*  row_ptr = (int*)walloc((size_t)(N + 1) * 4);
    int*  nextp   = (int*)walloc((size_t)N * 4);
    int2* csr_sw  = (int2*)walloc((size_t)E * 8);

    const int LDS_BYTES = 80 * 1024;
    const int MT = (N + 255) / 256;              // 391 M-tiles
    const int G  = (MT + 7) / 8;                 // m-groups of 8
    const int wgs = (N + 3) / 4;

    // ---- CSR build ----
    hipMemsetAsync(counts, 0, (size_t)N * 4, stream);
    count_dst_kernel<<<(E + 255) / 256, 256, 0, stream>>>(dst, counts, E);
    scan_kernel<<<1, 1024, 0, stream>>>(counts, row_ptr, N);
    hipMemcpyAsync(nextp, row_ptr, (size_t)N * 4, hipMemcpyDeviceToDevice, stream);
    fill_csr_kernel<<<(E + 255) / 256, 256, 0, stream>>>(src, dst, ew, nextp, csr_sw, E);

    // ---- conversions ----
    {
        size_t nx4 = (size_t)N * NFEAT / 4;
        split_f32_kernel<<<(int)((nx4 + 255) / 256), 256, 0, stream>>>(x, XHI, XLO, nx4);
    }
    split_wt_kernel<<<(NP1 * KP1 + 255) / 256, 256, 0, stream>>>(w1, W1HI, W1LO, NFEAT, H1, KP1, NP1);
    split_wt_kernel<<<(NP2 * KP2 + 255) / 256, 256, 0, stream>>>(w2, W2HI, W2LO, H1, H2, KP2, NP2);
    split_wt_kernel<<<(NP3 * KP3 + 255) / 256, 256, 0, stream>>>(w3, W3HI, W3LO, H2, NCLASS, KP3, NP3);

    // ---- layer 1 ----
    gemm_mfma_kernel<KP1, NT1><<<G * 8 * NT1, 256, LDS_BYTES, stream>>>(
        XHI, XLO, W1HI, W1LO, support, N, NP1, MT);
    spmm_relu_split_kernel<H1, NP1><<<wgs, 256, 0, stream>>>(row_ptr, csr_sw, support, b1, H1HI, H1LO, N);

    // ---- layer 2 ----
    gemm_mfma_kernel<KP2, NT2><<<G * 8 * NT2, 256, LDS_BYTES, stream>>>(
        H1HI, H1LO, W2HI, W2LO, support, N, NP2, MT);
    spmm_relu_split_kernel<H2, NP2><<<wgs, 256, 0, stream>>>(row_ptr, csr_sw, support, b2, H2HI, H2LO, N);

    // ---- layer 3 ----
    gemm_mfma_kernel<KP3, NT3><<<G * 8 * NT3, 256, LDS_BYTES, stream>>>(
        H2HI, H2LO, W3HI, W3LO, support, N, NP3, MT);
    spmm_softmax_kernel<<<wgs, 256, 0, stream>>>(row_ptr, csr_sw, support, b3, out, N);
}

// Round 6
// 1757.296 us; speedup vs baseline: 1.8096x; 1.0284x over previous
//
#include <hip/hip_runtime.h>
#include <hip/hip_bf16.h>
#include <hip/hip_fp16.h>
#include <math.h>

#define NFEAT 512
#define H1 300
#define H2 200
#define NCLASS 40

typedef __attribute__((ext_vector_type(8))) _Float16 half8;
typedef __attribute__((ext_vector_type(4))) float f32x4;
typedef __attribute__((ext_vector_type(2))) unsigned int u32x2;

__device__ __forceinline__ void stage16(const void* gptr, void* ldsptr) {
    __builtin_amdgcn_global_load_lds(
        (const __attribute__((address_space(1))) unsigned int*)gptr,
        (__attribute__((address_space(3))) unsigned int*)ldsptr,
        16, 0, 0);
}

__device__ __forceinline__ unsigned short f2h(float f) {
    return __half_as_ushort(__float2half(f));
}
__device__ __forceinline__ float h2f(unsigned short u) {
    return __half2float(__ushort_as_half(u));
}
__device__ __forceinline__ float2 h2f2(unsigned int u) {
    __half2 h = *reinterpret_cast<__half2*>(&u);
    return __half22float2(h);
}
__device__ __forceinline__ unsigned pack2h(float a, float b) {
    return (unsigned)f2h(a) | ((unsigned)f2h(b) << 16);
}

// ---------------- CSR construction ----------------

__global__ __launch_bounds__(256) void count_dst_kernel(const int* __restrict__ dst,
                                                        int* __restrict__ counts, int E) {
    int i = blockIdx.x * blockDim.x + threadIdx.x;
    if (i < E) atomicAdd(&counts[dst[i]], 1);
}

// serial-per-thread + one block scan; writes row_ptr and the nextp working copy
__global__ __launch_bounds__(1024) void scan_kernel(const int* __restrict__ counts,
                                                    int* __restrict__ row_ptr,
                                                    int* __restrict__ nextp, int N) {
    __shared__ int sums[1024];
    const int tid = threadIdx.x;
    const int CH = (N + 1023) >> 10;
    const int b = tid * CH;
    const int e = min(b + CH, N);
    int s = 0;
    for (int i = b; i < e; i++) s += counts[i];
    sums[tid] = s;
    __syncthreads();
    #pragma unroll
    for (int off = 1; off < 1024; off <<= 1) {
        int t = (tid >= off) ? sums[tid - off] : 0;
        __syncthreads();
        sums[tid] += t;
        __syncthreads();
    }
    int run = (tid > 0) ? sums[tid - 1] : 0;
    for (int i = b; i < e; i++) {
        row_ptr[i] = run;
        nextp[i] = run;
        run += counts[i];
    }
    if (tid == 0) row_ptr[N] = sums[1023];
}

__global__ __launch_bounds__(256) void fill_csr_kernel(const int* __restrict__ src,
                                                       const int* __restrict__ dst,
                                                       const float* __restrict__ ew,
                                                       int* __restrict__ next,
                                                       int2* __restrict__ csr_sw, int E) {
    int i = blockIdx.x * blockDim.x + threadIdx.x;
    if (i < E) {
        int d = dst[i];
        int pos = atomicAdd(&next[d], 1);
        csr_sw[pos] = make_int2(src[i], __float_as_int(ew[i]));
    }
}

// ---------------- X fp32 -> fp16 (vectorized) ----------------

__global__ __launch_bounds__(256) void cvt_x_kernel(const float* __restrict__ in,
                                                    unsigned short* __restrict__ out,
                                                    size_t n4) {
    size_t i = (size_t)blockIdx.x * 256 + threadIdx.x;
    if (i < n4) {
        float4 a = ((const float4*)in)[i];
        u32x2 w;
        w.x = pack2h(a.x, a.y);
        w.y = pack2h(a.z, a.w);
        *(u32x2*)(out + i * 4) = w;
    }
}

// ---------------- fused weight split: w [K][N] fp32 -> [NPAD][KPAD] fp16 hi/lo ----------------
// three weights in one launch; 262144 total elements = 1024 blocks x 256.

__global__ __launch_bounds__(256) void split_weights_kernel(
        const float* __restrict__ w1, const float* __restrict__ w2, const float* __restrict__ w3,
        unsigned short* __restrict__ W1H, unsigned short* __restrict__ W1L,
        unsigned short* __restrict__ W2H, unsigned short* __restrict__ W2L,
        unsigned short* __restrict__ W3H, unsigned short* __restrict__ W3L) {
    int i = blockIdx.x * 256 + threadIdx.x;
    const float* w; unsigned short *H, *L; int K, N, KP;
    if (i < 163840) {                       // 320*512
        w = w1; H = W1H; L = W1L; K = 512; N = 300; KP = 512;
    } else if (i < 163840 + 81920) {        // 256*320
        i -= 163840; w = w2; H = W2H; L = W2L; K = 300; N = 200; KP = 320;
    } else {                                // 64*256
        i -= 245760; w = w3; H = W3H; L = W3L; K = 200; N = 40; KP = 256;
    }
    int n = i / KP, k = i - n * KP;
    float a = (n < N && k < K) ? w[(size_t)k * N + n] : 0.f;
    unsigned short h = f2h(a);
    H[i] = h;
    L[i] = f2h(a - h2f(h));
}

// ---------------- fp16 MFMA GEMM (A single fp16, B split fp16 hi/lo) ----------------
// C[M x NP] fp16 = A[M x KPAD] @ (Bhi+Blo)^T  (B stored [NPAD][KPAD])
// 1D grid, XCD-aware swizzle (blocks sharing an M-tile: id == x mod 8, adjacent).
// tile 256x64, BK=64; 2 MFMA passes per frag pair. LDS 48 KB -> 3 blocks/CU.

template <int KPAD, int NT>
__global__ __launch_bounds__(256, 3) void gemm_f16_kernel(
        const unsigned short* __restrict__ A,
        const unsigned short* __restrict__ Bhi, const unsigned short* __restrict__ Blo,
        unsigned short* __restrict__ C, int M, int NP, int MT) {
    extern __shared__ short lds[];
    short* As    = lds;               // 256*64 = 16384 shorts (32 KB)
    short* Bs_hi = lds + 16384;       // 64*64  = 4096
    short* Bs_lo = lds + 20480;       // 4096 -> 48 KB total

    const int id = blockIdx.x;
    const int g  = id / (8 * NT);
    const int r  = id % (8 * NT);
    const int nt = r >> 3;
    const int x  = r & 7;
    const int mt = g * 8 + x;
    if (mt >= MT) return;

    const int tid = threadIdx.x;
    const int wave = tid >> 6, lane = tid & 63;
    const int lm = lane & 15, quad = lane >> 4;
    const int bm = mt * 256, bn = nt * 64;

    f32x4 acc[4][4] = {};

    for (int k0 = 0; k0 < KPAD; k0 += 64) {
        #pragma unroll
        for (int i = 0; i < 8; i++) {
            int t = i * 256 + tid;
            int m = t >> 3;
            int c = (t & 7) ^ (m & 7);
            int row = bm + m; row = row < M ? row : M - 1;
            size_t goff = (size_t)row * KPAD + (size_t)(k0 + c * 8);
            int lbase = (i * 256 + wave * 64) * 8;
            stage16(A + goff, As + lbase);
        }
        #pragma unroll
        for (int i = 0; i < 2; i++) {
            int t = i * 256 + tid;
            int n = t >> 3;
            int c = (t & 7) ^ (n & 7);
            size_t goff = (size_t)(bn + n) * KPAD + (size_t)(k0 + c * 8);
            int lbase = (i * 256 + wave * 64) * 8;
            stage16(Bhi + goff, Bs_hi + lbase);
            stage16(Blo + goff, Bs_lo + lbase);
        }
        __syncthreads();

        #pragma unroll
        for (int h = 0; h < 2; h++) {
            const int cidx = h * 4 + quad;
            half8 a[4], bh[4], bl[4];
            #pragma unroll
            for (int i = 0; i < 4; i++) {
                int m = wave * 64 + i * 16 + lm;
                int off = (m * 8 + (cidx ^ (m & 7))) * 8;
                a[i] = *(const half8*)(As + off);
            }
            #pragma unroll
            for (int j = 0; j < 4; j++) {
                int n = j * 16 + lm;
                int off = (n * 8 + (cidx ^ (n & 7))) * 8;
                bh[j] = *(const half8*)(Bs_hi + off);
                bl[j] = *(const half8*)(Bs_lo + off);
            }
            #pragma unroll
            for (int i = 0; i < 4; i++)
                #pragma unroll
                for (int j = 0; j < 4; j++) {
                    acc[i][j] = __builtin_amdgcn_mfma_f32_16x16x32_f16(a[i], bh[j], acc[i][j], 0, 0, 0);
                    acc[i][j] = __builtin_amdgcn_mfma_f32_16x16x32_f16(a[i], bl[j], acc[i][j], 0, 0, 0);
                }
        }
        __syncthreads();
    }

    #pragma unroll
    for (int i = 0; i < 4; i++) {
        #pragma unroll
        for (int j = 0; j < 4; j++) {
            #pragma unroll
            for (int r2 = 0; r2 < 4; r2++) {
                int row = bm + wave * 64 + i * 16 + quad * 4 + r2;
                int col = bn + j * 16 + lm;
                if (row < M)
                    C[(size_t)row * NP + col] = f2h(acc[i][j][r2]);
            }
        }
    }
}

// ---------------- SpMM (CSR by dst), one wave per dst row, fp16 gather ----------------
// src/w wave-uniform -> readfirstlane (saddr gathers); 4-edge unroll.
// epilogue writes relu result as SINGLE fp16, row stride NP, zero-padded.

template <int F, int NP>
__global__ __launch_bounds__(256) void spmm_relu_f16_kernel(
        const int* __restrict__ row_ptr, const int2* __restrict__ csr_sw,
        const unsigned short* __restrict__ support, const float* __restrict__ bias,
        unsigned short* __restrict__ outp, int N) {
    constexpr int F4 = F / 4;
    constexpr int NP4 = NP / 4;
    constexpr int NCH = (F4 + 63) / 64;
    constexpr int NCHW = (NP4 + 63) / 64;

    int row = blockIdx.x * 4 + (threadIdx.x >> 6);
    int lane = threadIdx.x & 63;
    if (row >= N) return;
    int beg = row_ptr[row], end = row_ptr[row + 1];

    float acc[NCHW][4] = {};

    int e = beg;
    for (; e + 3 < end; e += 4) {
        int s_[4]; float w_[4];
        #pragma unroll
        for (int q = 0; q < 4; q++) {
            int2 sw = csr_sw[e + q];
            s_[q] = __builtin_amdgcn_readfirstlane(sw.x);
            w_[q] = __uint_as_float((unsigned)__builtin_amdgcn_readfirstlane(sw.y));
        }
        u32x2 u[4][NCH];
        #pragma unroll
        for (int q = 0; q < 4; q++) {
            const unsigned short* sp = support + (size_t)s_[q] * NP;
            #pragma unroll
            for (int j = 0; j < NCH; j++) {
                int f4 = j * 64 + lane;
                if (f4 < F4) u[q][j] = *(const u32x2*)(sp + f4 * 4);
            }
        }
        #pragma unroll
        for (int q = 0; q < 4; q++) {
            #pragma unroll
            for (int j = 0; j < NCH; j++) {
                int f4 = j * 64 + lane;
                if (f4 < F4) {
                    float2 a0 = h2f2(u[q][j].x), a1 = h2f2(u[q][j].y);
                    acc[j][0] += w_[q] * a0.x;
                    acc[j][1] += w_[q] * a0.y;
                    acc[j][2] += w_[q] * a1.x;
                    acc[j][3] += w_[q] * a1.y;
                }
            }
        }
    }
    for (; e < end; e++) {
        int2 sw = csr_sw[e];
        int ssrc = __builtin_amdgcn_readfirstlane(sw.x);
        float w0 = __uint_as_float((unsigned)__builtin_amdgcn_readfirstlane(sw.y));
        const unsigned short* sp = support + (size_t)ssrc * NP;
        #pragma unroll
        for (int j = 0; j < NCH; j++) {
            int f4 = j * 64 + lane;
            if (f4 < F4) {
                u32x2 u = *(const u32x2*)(sp + f4 * 4);
                float2 a0 = h2f2(u.x), a1 = h2f2(u.y);
                acc[j][0] += w0 * a0.x;
                acc[j][1] += w0 * a0.y;
                acc[j][2] += w0 * a1.x;
                acc[j][3] += w0 * a1.y;
            }
        }
    }

    #pragma unroll
    for (int j = 0; j < NCHW; j++) {
        int f4 = j * 64 + lane;
        if (f4 < NP4) {
            bool real = f4 < F4;
            float4 bb = real ? ((const float4*)bias)[f4] : make_float4(0, 0, 0, 0);
            float v0 = real ? fmaxf(acc[j][0] + bb.x, 0.f) : 0.f;
            float v1 = real ? fmaxf(acc[j][1] + bb.y, 0.f) : 0.f;
            float v2 = real ? fmaxf(acc[j][2] + bb.z, 0.f) : 0.f;
            float v3 = real ? fmaxf(acc[j][3] + bb.w, 0.f) : 0.f;
            u32x2 w;
            w.x = pack2h(v0, v1);
            w.y = pack2h(v2, v3);
            *(u32x2*)(outp + (size_t)row * NP + f4 * 4) = w;
        }
    }
}

// layer 3: aggregation (F=40, stride 64 fp16) + bias + softmax fused
__global__ __launch_bounds__(256) void spmm_softmax_kernel(
        const int* __restrict__ row_ptr, const int2* __restrict__ csr_sw,
        const unsigned short* __restrict__ support, const float* __restrict__ bias,
        float* __restrict__ out, int N) {
    int row = blockIdx.x * 4 + (threadIdx.x >> 6);
    int lane = threadIdx.x & 63;
    if (row >= N) return;
    int beg = row_ptr[row], end = row_ptr[row + 1];
    const bool act = lane < NCLASS / 4;   // 10 lanes
    float acc[4] = {0.f, 0.f, 0.f, 0.f};
    int e = beg;
    for (; e + 1 < end; e += 2) {
        int2 sw0 = csr_sw[e];
        int2 sw1 = csr_sw[e + 1];
        int  s0 = __builtin_amdgcn_readfirstlane(sw0.x);
        int  s1 = __builtin_amdgcn_readfirstlane(sw1.x);
        float w0 = __uint_as_float((unsigned)__builtin_amdgcn_readfirstlane(sw0.y));
        float w1 = __uint_as_float((unsigned)__builtin_amdgcn_readfirstlane(sw1.y));
        if (act) {
            u32x2 u0 = *(const u32x2*)(support + (size_t)s0 * 64 + lane * 4);
            u32x2 u1 = *(const u32x2*)(support + (size_t)s1 * 64 + lane * 4);
            float2 a0 = h2f2(u0.x), a1 = h2f2(u0.y);
            float2 c0 = h2f2(u1.x), c1 = h2f2(u1.y);
            acc[0] += w0 * a0.x + w1 * c0.x;
            acc[1] += w0 * a0.y + w1 * c0.y;
            acc[2] += w0 * a1.x + w1 * c1.x;
            acc[3] += w0 * a1.y + w1 * c1.y;
        }
    }
    if (e < end) {
        int2 sw = csr_sw[e];
        int  s0 = __builtin_amdgcn_readfirstlane(sw.x);
        float w0 = __uint_as_float((unsigned)__builtin_amdgcn_readfirstlane(sw.y));
        if (act) {
            u32x2 u = *(const u32x2*)(support + (size_t)s0 * 64 + lane * 4);
            float2 a0 = h2f2(u.x), a1 = h2f2(u.y);
            acc[0] += w0 * a0.x;
            acc[1] += w0 * a0.y;
            acc[2] += w0 * a1.x;
            acc[3] += w0 * a1.y;
        }
    }
    float v[4];
    float m = -INFINITY;
    if (act) {
        float4 bb = ((const float4*)bias)[lane];
        v[0] = acc[0] + bb.x; v[1] = acc[1] + bb.y;
        v[2] = acc[2] + bb.z; v[3] = acc[3] + bb.w;
        m = fmaxf(fmaxf(v[0], v[1]), fmaxf(v[2], v[3]));
    }
    #pragma unroll
    for (int off = 8; off; off >>= 1) m = fmaxf(m, __shfl_xor(m, off));
    float s = 0.f, ex[4];
    if (act) {
        #pragma unroll
        for (int k = 0; k < 4; k++) { ex[k] = expf(v[k] - m); s += ex[k]; }
    }
    #pragma unroll
    for (int off = 8; off; off >>= 1) s += __shfl_xor(s, off);
    if (act) {
        float inv = 1.f / s;
        float4 r = make_float4(ex[0] * inv, ex[1] * inv, ex[2] * inv, ex[3] * inv);
        ((float4*)(out + (size_t)row * NCLASS))[lane] = r;
    }
}

// ---------------- launch ----------------

extern "C" void kernel_launch(void* const* d_in, const int* in_sizes, int n_in,
                              void* d_out, int out_size, void* d_ws, size_t ws_size,
                              hipStream_t stream) {
    const float* x   = (const float*)d_in[0];
    const int*   ei  = (const int*)d_in[1];
    const float* ew  = (const float*)d_in[2];
    const float* w1  = (const float*)d_in[3];
    const float* b1  = (const float*)d_in[4];
    const float* w2  = (const float*)d_in[5];
    const float* b2  = (const float*)d_in[6];
    const float* w3  = (const float*)d_in[7];
    const float* b3  = (const float*)d_in[8];
    float* out = (float*)d_out;

    const int N = in_sizes[0] / NFEAT;   // 100000
    const int E = in_sizes[2];           // 3200000
    const int* src = ei;
    const int* dst = ei + E;

    const int KP1 = 512, NP1 = 320, NT1 = 5;   // layer1: K=512, N=300
    const int KP2 = 320, NP2 = 256, NT2 = 4;   // layer2: K=300, N=200
    const int KP3 = 256, NP3 = 64,  NT3 = 1;   // layer3: K=200, N=40

    char* base = (char*)d_ws;
    // Region A (0..102.4MB): X fp16; overlaid by H1 (64MB) / H2 (51.2MB) after gemm1
    unsigned short* XH  = (unsigned short*)(base);   // 100000*512*2 = 102,400,000
    unsigned short* H1H = (unsigned short*)(base);   // 100000*320*2 = 64,000,000
    unsigned short* H2H = (unsigned short*)(base);   // 100000*256*2 = 51,200,000

    // Region B: support fp16 (max 100000*320*2 = 64MB)
    unsigned short* support = (unsigned short*)(base + 102400256);

    // Region C: weights + CSR
    size_t wo = 102400256 + 64000256;
    auto walloc = [&](size_t bytes) { void* r = base + wo; wo += (bytes + 255) & ~(size_t)255; return r; };
    unsigned short* W1H = (unsigned short*)walloc((size_t)NP1 * KP1 * 2);
    unsigned short* W1L = (unsigned short*)walloc((size_t)NP1 * KP1 * 2);
    unsigned short* W2H = (unsigned short*)walloc((size_t)NP2 * KP2 * 2);
    unsigned short* W2L = (unsigned short*)walloc((size_t)NP2 * KP2 * 2);
    unsigned short* W3H = (unsigned short*)walloc((size_t)NP3 * KP3 * 2);
    unsigned short* W3L = (unsigned short*)walloc((size_t)NP3 * KP3 * 2);
    int*  counts  = (int*)walloc((size_t)N * 4);
    int*  row_ptr = (int*)walloc((size_t)(N + 1) * 4);
    int*  nextp   = (int*)walloc((size_t)N * 4);
    int2* csr_sw  = (int2*)walloc((size_t)E * 8);

    const int LDS_BYTES = 48 * 1024;
    const int MT = (N + 255) / 256;              // 391 M-tiles
    const int G  = (MT + 7) / 8;
    const int wgs = (N + 3) / 4;

    // ---- CSR build ----
    hipMemsetAsync(counts, 0, (size_t)N * 4, stream);
    count_dst_kernel<<<(E + 255) / 256, 256, 0, stream>>>(dst, counts, E);
    scan_kernel<<<1, 1024, 0, stream>>>(counts, row_ptr, nextp, N);
    fill_csr_kernel<<<(E + 255) / 256, 256, 0, stream>>>(src, dst, ew, nextp, csr_sw, E);

    // ---- conversions ----
    {
        size_t nx4 = (size_t)N * NFEAT / 4;
        cvt_x_kernel<<<(int)((nx4 + 255) / 256), 256, 0, stream>>>(x, XH, nx4);
    }
    split_weights_kernel<<<1024, 256, 0, stream>>>(w1, w2, w3, W1H, W1L, W2H, W2L, W3H, W3L);

    // ---- layer 1 ----
    gemm_f16_kernel<KP1, NT1><<<G * 8 * NT1, 256, LDS_BYTES, stream>>>(
        XH, W1H, W1L, support, N, NP1, MT);
    spmm_relu_f16_kernel<H1, NP1><<<wgs, 256, 0, stream>>>(row_ptr, csr_sw, support, b1, H1H, N);

    // ---- layer 2 ----
    gemm_f16_kernel<KP2, NT2><<<G * 8 * NT2, 256, LDS_BYTES, stream>>>(
        H1H, W2H, W2L, support, N, NP2, MT);
    spmm_relu_f16_kernel<H2, NP2><<<wgs, 256, 0, stream>>>(row_ptr, csr_sw, support, b2, H2H, N);

    // ---- layer 3 ----
    gemm_f16_kernel<KP3, NT3><<<G * 8 * NT3, 256, LDS_BYTES, stream>>>(
        H2H, W3H, W3L, support, N, NP3, MT);
    spmm_softmax_kernel<<<wgs, 256, 0, stream>>>(row_ptr, csr_sw, support, b3, out, N);
}

// Round 7
// 1669.711 us; speedup vs baseline: 1.9046x; 1.0525x over previous
//
#include <hip/hip_runtime.h>
#include <hip/hip_bf16.h>
#include <hip/hip_fp16.h>
#include <math.h>

#define NFEAT 512
#define H1 300
#define H2 200
#define NCLASS 40

typedef __attribute__((ext_vector_type(8))) _Float16 half8;
typedef __attribute__((ext_vector_type(4))) float f32x4;
typedef __attribute__((ext_vector_type(2))) unsigned int u32x2;

__device__ __forceinline__ void stage16(const void* gptr, void* ldsptr) {
    __builtin_amdgcn_global_load_lds(
        (const __attribute__((address_space(1))) unsigned int*)gptr,
        (__attribute__((address_space(3))) unsigned int*)ldsptr,
        16, 0, 0);
}

__device__ __forceinline__ unsigned short f2h(float f) {
    return __half_as_ushort(__float2half(f));
}
__device__ __forceinline__ float h2f(unsigned short u) {
    return __half2float(__ushort_as_half(u));
}
__device__ __forceinline__ float2 h2f2(unsigned int u) {
    __half2 h = *reinterpret_cast<__half2*>(&u);
    return __half22float2(h);
}
__device__ __forceinline__ unsigned pack2h(float a, float b) {
    return (unsigned)f2h(a) | ((unsigned)f2h(b) << 16);
}

// ---------------- CSR construction ----------------

__global__ __launch_bounds__(256) void count_dst_kernel(const int* __restrict__ dst,
                                                        int* __restrict__ counts, int E) {
    int i = blockIdx.x * blockDim.x + threadIdx.x;
    if (i < E) atomicAdd(&counts[dst[i]], 1);
}

__global__ __launch_bounds__(1024) void scan_kernel(const int* __restrict__ counts,
                                                    int* __restrict__ row_ptr,
                                                    int* __restrict__ nextp, int N) {
    __shared__ int sums[1024];
    const int tid = threadIdx.x;
    const int CH = (N + 1023) >> 10;
    const int b = tid * CH;
    const int e = min(b + CH, N);
    int s = 0;
    for (int i = b; i < e; i++) s += counts[i];
    sums[tid] = s;
    __syncthreads();
    #pragma unroll
    for (int off = 1; off < 1024; off <<= 1) {
        int t = (tid >= off) ? sums[tid - off] : 0;
        __syncthreads();
        sums[tid] += t;
        __syncthreads();
    }
    int run = (tid > 0) ? sums[tid - 1] : 0;
    for (int i = b; i < e; i++) {
        row_ptr[i] = run;
        nextp[i] = run;
        run += counts[i];
    }
    if (tid == 0) row_ptr[N] = sums[1023];
}

__global__ __launch_bounds__(256) void fill_csr_kernel(const int* __restrict__ src,
                                                       const int* __restrict__ dst,
                                                       const float* __restrict__ ew,
                                                       int* __restrict__ next,
                                                       int2* __restrict__ csr_sw, int E) {
    int i = blockIdx.x * blockDim.x + threadIdx.x;
    if (i < E) {
        int d = dst[i];
        int pos = atomicAdd(&next[d], 1);
        csr_sw[pos] = make_int2(src[i], __float_as_int(ew[i]));
    }
}

// ---------------- fused weight split: w [K][N] fp32 -> [NPAD][KPAD] fp16 hi/lo ----------------

__global__ __launch_bounds__(256) void split_weights_kernel(
        const float* __restrict__ w1, const float* __restrict__ w2, const float* __restrict__ w3,
        unsigned short* __restrict__ W1H, unsigned short* __restrict__ W1L,
        unsigned short* __restrict__ W2H, unsigned short* __restrict__ W2L,
        unsigned short* __restrict__ W3H, unsigned short* __restrict__ W3L) {
    int i = blockIdx.x * 256 + threadIdx.x;
    const float* w; unsigned short *H, *L; int K, N, KP;
    if (i < 163840) {                       // 320*512
        w = w1; H = W1H; L = W1L; K = 512; N = 300; KP = 512;
    } else if (i < 163840 + 81920) {        // 256*320
        i -= 163840; w = w2; H = W2H; L = W2L; K = 300; N = 200; KP = 320;
    } else {                                // 64*256
        i -= 245760; w = w3; H = W3H; L = W3L; K = 200; N = 40; KP = 256;
    }
    int n = i / KP, k = i - n * KP;
    float a = (n < N && k < K) ? w[(size_t)k * N + n] : 0.f;
    unsigned short h = f2h(a);
    H[i] = h;
    L[i] = f2h(a - h2f(h));
}

// ---------------- fp16 MFMA GEMM: B-only LDS, A direct global->VGPR ----------------
// C[M x NP] fp16 = A[M x KPAD] @ (Bhi+Blo)^T  (B stored [NPAD][KPAD])
// AF32: A is fp32 (layer 1 reads X directly, converts in-register).
// 1D grid, XCD-aware swizzle (blocks sharing an M-tile: id == x mod 8, adjacent).
// tile 256x64, BK=64; LDS 16 KB (B hi/lo only).

template <int KPAD, int NT, bool AF32>
__global__ __launch_bounds__(256, 3) void gemm_f16_kernel(
        const void* __restrict__ A_,
        const unsigned short* __restrict__ Bhi, const unsigned short* __restrict__ Blo,
        unsigned short* __restrict__ C, int M, int NP, int MT) {
    __shared__ short Bs_hi[4096];
    __shared__ short Bs_lo[4096];

    const int id = blockIdx.x;
    const int g  = id / (8 * NT);
    const int r  = id % (8 * NT);
    const int nt = r >> 3;
    const int x  = r & 7;
    const int mt = g * 8 + x;
    if (mt >= MT) return;

    const int tid = threadIdx.x;
    const int wave = tid >> 6, lane = tid & 63;
    const int lm = lane & 15, quad = lane >> 4;
    const int bm = mt * 256, bn = nt * 64;

    f32x4 acc[4][4] = {};

    for (int k0 = 0; k0 < KPAD; k0 += 64) {
        // ---- stage B tile 64x64 hi+lo (swizzled) ----
        #pragma unroll
        for (int i = 0; i < 2; i++) {
            int t = i * 256 + tid;
            int n = t >> 3;
            int c = (t & 7) ^ (n & 7);
            size_t goff = (size_t)(bn + n) * KPAD + (size_t)(k0 + c * 8);
            int lbase = (i * 256 + wave * 64) * 8;
            stage16(Bhi + goff, Bs_hi + lbase);
            stage16(Blo + goff, Bs_lo + lbase);
        }
        __syncthreads();

        #pragma unroll
        for (int h = 0; h < 2; h++) {
            const int cidx = h * 4 + quad;
            half8 a[4], bh[4], bl[4];
            #pragma unroll
            for (int i = 0; i < 4; i++) {
                int row = bm + wave * 64 + i * 16 + lm;
                row = row < M ? row : M - 1;
                size_t off = (size_t)row * KPAD + (size_t)(k0 + cidx * 8);
                if (AF32) {
                    const float* ap = (const float*)A_ + off;
                    float4 p = *(const float4*)ap;
                    float4 q = *(const float4*)(ap + 4);
                    half8 t8;
                    t8[0] = (_Float16)p.x; t8[1] = (_Float16)p.y;
                    t8[2] = (_Float16)p.z; t8[3] = (_Float16)p.w;
                    t8[4] = (_Float16)q.x; t8[5] = (_Float16)q.y;
                    t8[6] = (_Float16)q.z; t8[7] = (_Float16)q.w;
                    a[i] = t8;
                } else {
                    a[i] = *(const half8*)((const unsigned short*)A_ + off);
                }
            }
            #pragma unroll
            for (int j = 0; j < 4; j++) {
                int n = j * 16 + lm;
                int off = (n * 8 + (cidx ^ (n & 7))) * 8;
                bh[j] = *(const half8*)(Bs_hi + off);
                bl[j] = *(const half8*)(Bs_lo + off);
            }
            #pragma unroll
            for (int i = 0; i < 4; i++)
                #pragma unroll
                for (int j = 0; j < 4; j++) {
                    acc[i][j] = __builtin_amdgcn_mfma_f32_16x16x32_f16(a[i], bh[j], acc[i][j], 0, 0, 0);
                    acc[i][j] = __builtin_amdgcn_mfma_f32_16x16x32_f16(a[i], bl[j], acc[i][j], 0, 0, 0);
                }
        }
        __syncthreads();
    }

    #pragma unroll
    for (int i = 0; i < 4; i++) {
        #pragma unroll
        for (int j = 0; j < 4; j++) {
            #pragma unroll
            for (int r2 = 0; r2 < 4; r2++) {
                int row = bm + wave * 64 + i * 16 + quad * 4 + r2;
                int col = bn + j * 16 + lm;
                if (row < M)
                    C[(size_t)row * NP + col] = f2h(acc[i][j][r2]);
            }
        }
    }
}

// ---------------- SpMM (CSR by dst), one wave per dst row, fp16 gather ----------------

template <int F, int NP>
__global__ __launch_bounds__(256) void spmm_relu_f16_kernel(
        const int* __restrict__ row_ptr, const int2* __restrict__ csr_sw,
        const unsigned short* __restrict__ support, const float* __restrict__ bias,
        unsigned short* __restrict__ outp, int N) {
    constexpr int F4 = F / 4;
    constexpr int NP4 = NP / 4;
    constexpr int NCH = (F4 + 63) / 64;
    constexpr int NCHW = (NP4 + 63) / 64;

    int row = blockIdx.x * 4 + (threadIdx.x >> 6);
    int lane = threadIdx.x & 63;
    if (row >= N) return;
    int beg = row_ptr[row], end = row_ptr[row + 1];

    float acc[NCHW][4] = {};

    int e = beg;
    for (; e + 3 < end; e += 4) {
        int s_[4]; float w_[4];
        #pragma unroll
        for (int q = 0; q < 4; q++) {
            int2 sw = csr_sw[e + q];
            s_[q] = __builtin_amdgcn_readfirstlane(sw.x);
            w_[q] = __uint_as_float((unsigned)__builtin_amdgcn_readfirstlane(sw.y));
        }
        u32x2 u[4][NCH];
        #pragma unroll
        for (int q = 0; q < 4; q++) {
            const unsigned short* sp = support + (size_t)s_[q] * NP;
            #pragma unroll
            for (int j = 0; j < NCH; j++) {
                int f4 = j * 64 + lane;
                if (f4 < F4) u[q][j] = *(const u32x2*)(sp + f4 * 4);
            }
        }
        #pragma unroll
        for (int q = 0; q < 4; q++) {
            #pragma unroll
            for (int j = 0; j < NCH; j++) {
                int f4 = j * 64 + lane;
                if (f4 < F4) {
                    float2 a0 = h2f2(u[q][j].x), a1 = h2f2(u[q][j].y);
                    acc[j][0] += w_[q] * a0.x;
                    acc[j][1] += w_[q] * a0.y;
                    acc[j][2] += w_[q] * a1.x;
                    acc[j][3] += w_[q] * a1.y;
                }
            }
        }
    }
    for (; e < end; e++) {
        int2 sw = csr_sw[e];
        int ssrc = __builtin_amdgcn_readfirstlane(sw.x);
        float w0 = __uint_as_float((unsigned)__builtin_amdgcn_readfirstlane(sw.y));
        const unsigned short* sp = support + (size_t)ssrc * NP;
        #pragma unroll
        for (int j = 0; j < NCH; j++) {
            int f4 = j * 64 + lane;
            if (f4 < F4) {
                u32x2 u = *(const u32x2*)(sp + f4 * 4);
                float2 a0 = h2f2(u.x), a1 = h2f2(u.y);
                acc[j][0] += w0 * a0.x;
                acc[j][1] += w0 * a0.y;
                acc[j][2] += w0 * a1.x;
                acc[j][3] += w0 * a1.y;
            }
        }
    }

    #pragma unroll
    for (int j = 0; j < NCHW; j++) {
        int f4 = j * 64 + lane;
        if (f4 < NP4) {
            bool real = f4 < F4;
            float4 bb = real ? ((const float4*)bias)[f4] : make_float4(0, 0, 0, 0);
            float v0 = real ? fmaxf(acc[j][0] + bb.x, 0.f) : 0.f;
            float v1 = real ? fmaxf(acc[j][1] + bb.y, 0.f) : 0.f;
            float v2 = real ? fmaxf(acc[j][2] + bb.z, 0.f) : 0.f;
            float v3 = real ? fmaxf(acc[j][3] + bb.w, 0.f) : 0.f;
            u32x2 w;
            w.x = pack2h(v0, v1);
            w.y = pack2h(v2, v3);
            *(u32x2*)(outp + (size_t)row * NP + f4 * 4) = w;
        }
    }
}

// layer 3: aggregation (F=40, stride 64 fp16) + bias + softmax fused.
// 3 edges per wave-iteration across lane-groups of 20 (2 fp16/lane),
// cross-group shuffle-combine, softmax over 20 lanes (2 classes/lane).

__global__ __launch_bounds__(256) void spmm_softmax_kernel(
        const int* __restrict__ row_ptr, const int2* __restrict__ csr_sw,
        const unsigned short* __restrict__ support, const float* __restrict__ bias,
        float* __restrict__ out, int N) {
    int row = blockIdx.x * 4 + (threadIdx.x >> 6);
    int lane = threadIdx.x & 63;
    if (row >= N) return;
    int beg = row_ptr[row], end = row_ptr[row + 1];

    const int g = lane / 20;           // 0,1,2 active; 3 = idle lanes 60-63
    const int t = lane - g * 20;       // 0..19 (class dword index)
    const bool lact = lane < 60;

    float a0 = 0.f, a1 = 0.f;
    for (int e = beg; e < end; e += 3) {
        int ei = e + g;
        bool v = lact && (ei < end);
        int2 sw = csr_sw[v ? ei : beg];
        float w = v ? __int_as_float(sw.y) : 0.f;
        unsigned u = *(const unsigned*)(support + (size_t)sw.x * 64 + t * 2);
        float2 aa = h2f2(u);
        a0 += w * aa.x;
        a1 += w * aa.y;
    }
    // combine the 3 group partials into lanes 0..19
    a0 += __shfl(a0, lane + 20) + __shfl(a0, lane + 40);
    a1 += __shfl(a1, lane + 20) + __shfl(a1, lane + 40);

    const bool act = lane < 20;
    float v0 = 0.f, v1 = 0.f, m = -INFINITY;
    if (act) {
        float2 bb = ((const float2*)bias)[t];
        v0 = a0 + bb.x;
        v1 = a1 + bb.y;
        m = fmaxf(v0, v1);
    }
    #pragma unroll
    for (int off = 16; off; off >>= 1) m = fmaxf(m, __shfl_xor(m, off));
    float e0 = 0.f, e1 = 0.f;
    if (act) { e0 = expf(v0 - m); e1 = expf(v1 - m); }
    float s = e0 + e1;
    #pragma unroll
    for (int off = 16; off; off >>= 1) s += __shfl_xor(s, off);
    if (act) {
        float inv = 1.f / s;
        *(float2*)(out + (size_t)row * NCLASS + t * 2) = make_float2(e0 * inv, e1 * inv);
    }
}

// ---------------- launch ----------------

extern "C" void kernel_launch(void* const* d_in, const int* in_sizes, int n_in,
                              void* d_out, int out_size, void* d_ws, size_t ws_size,
                              hipStream_t stream) {
    const float* x   = (const float*)d_in[0];
    const int*   ei  = (const int*)d_in[1];
    const float* ew  = (const float*)d_in[2];
    const float* w1  = (const float*)d_in[3];
    const float* b1  = (const float*)d_in[4];
    const float* w2  = (const float*)d_in[5];
    const float* b2  = (const float*)d_in[6];
    const float* w3  = (const float*)d_in[7];
    const float* b3  = (const float*)d_in[8];
    float* out = (float*)d_out;

    const int N = in_sizes[0] / NFEAT;   // 100000
    const int E = in_sizes[2];           // 3200000
    const int* src = ei;
    const int* dst = ei + E;

    const int KP1 = 512, NP1 = 320, NT1 = 5;   // layer1: K=512, N=300
    const int KP2 = 320, NP2 = 256, NT2 = 4;   // layer2: K=300, N=200
    const int KP3 = 256, NP3 = 64,  NT3 = 1;   // layer3: K=200, N=40

    char* base = (char*)d_ws;
    // Region A: H1 (64MB) / H2 (51.2MB, overlays H1 after gemm2 consumed it)
    unsigned short* H1H = (unsigned short*)(base);   // 100000*320*2 = 64,000,000
    unsigned short* H2H = (unsigned short*)(base);   // 100000*256*2 = 51,200,000

    // Region B: support fp16 (max 100000*320*2 = 64MB)
    unsigned short* support = (unsigned short*)(base + 102400256);

    // Region C: weights + CSR
    size_t wo = 102400256 + 64000256;
    auto walloc = [&](size_t bytes) { void* r = base + wo; wo += (bytes + 255) & ~(size_t)255; return r; };
    unsigned short* W1H = (unsigned short*)walloc((size_t)NP1 * KP1 * 2);
    unsigned short* W1L = (unsigned short*)walloc((size_t)NP1 * KP1 * 2);
    unsigned short* W2H = (unsigned short*)walloc((size_t)NP2 * KP2 * 2);
    unsigned short* W2L = (unsigned short*)walloc((size_t)NP2 * KP2 * 2);
    unsigned short* W3H = (unsigned short*)walloc((size_t)NP3 * KP3 * 2);
    unsigned short* W3L = (unsigned short*)walloc((size_t)NP3 * KP3 * 2);
    int*  counts  = (int*)walloc((size_t)N * 4);
    int*  row_ptr = (int*)walloc((size_t)(N + 1) * 4);
    int*  nextp   = (int*)walloc((size_t)N * 4);
    int2* csr_sw  = (int2*)walloc((size_t)E * 8);

    const int MT = (N + 255) / 256;              // 391 M-tiles
    const int G  = (MT + 7) / 8;
    const int wgs = (N + 3) / 4;

    // ---- CSR build ----
    hipMemsetAsync(counts, 0, (size_t)N * 4, stream);
    count_dst_kernel<<<(E + 255) / 256, 256, 0, stream>>>(dst, counts, E);
    scan_kernel<<<1, 1024, 0, stream>>>(counts, row_ptr, nextp, N);
    fill_csr_kernel<<<(E + 255) / 256, 256, 0, stream>>>(src, dst, ew, nextp, csr_sw, E);

    // ---- weight conversion ----
    split_weights_kernel<<<1024, 256, 0, stream>>>(w1, w2, w3, W1H, W1L, W2H, W2L, W3H, W3L);

    // ---- layer 1 (A = fp32 X, converted in-register) ----
    gemm_f16_kernel<KP1, NT1, true><<<G * 8 * NT1, 256, 0, stream>>>(
        x, W1H, W1L, support, N, NP1, MT);
    spmm_relu_f16_kernel<H1, NP1><<<wgs, 256, 0, stream>>>(row_ptr, csr_sw, support, b1, H1H, N);

    // ---- layer 2 ----
    gemm_f16_kernel<KP2, NT2, false><<<G * 8 * NT2, 256, 0, stream>>>(
        H1H, W2H, W2L, support, N, NP2, MT);
    spmm_relu_f16_kernel<H2, NP2><<<wgs, 256, 0, stream>>>(row_ptr, csr_sw, support, b2, H2H, N);

    // ---- layer 3 ----
    gemm_f16_kernel<KP3, NT3, false><<<G * 8 * NT3, 256, 0, stream>>>(
        H2H, W3H, W3L, support, N, NP3, MT);
    spmm_softmax_kernel<<<wgs, 256, 0, stream>>>(row_ptr, csr_sw, support, b3, out, N);
}